// Round 10
// baseline (3775.588 us; speedup 1.0000x reference)
//
#include <hip/hip_runtime.h>
#include <math.h>

#define H_ 12
#define STEPS_ 12
#define ALPHA_ 0.1f
#define EPS_ 1e-5f
#define BETA_ 0.125f          // 1/sqrt(64)
#define B2L_ 0.1803368801111204f   // BETA_ * log2(e)
#define L2E_ 1.4426950408889634f
#define NTOK 8192

typedef unsigned short u16;
typedef __attribute__((ext_vector_type(8))) u16 u16x8;
typedef __attribute__((ext_vector_type(4))) u16 u16x4;
typedef __attribute__((ext_vector_type(4))) float f32x4;
typedef __attribute__((ext_vector_type(8))) __bf16 bf16x8;

#define MFMA __builtin_amdgcn_mfma_f32_16x16x32_bf16
#define EXP2F(x) __builtin_amdgcn_exp2f(x)

__device__ __forceinline__ u16 f2bf(float x) {
    unsigned u = __float_as_uint(x);
    u += 0x7FFFu + ((u >> 16) & 1u);
    return (u16)(u >> 16);
}
__device__ __forceinline__ float bf2f(u16 u) {
    return __uint_as_float(((unsigned)u) << 16);
}
// truncation pack (1 VALU) for positive P values — ≤0.4% rel err, RTZ
__device__ __forceinline__ u16 f2bf_rz(float x) {
    return (u16)(__float_as_uint(x) >> 16);
}

// async global->LDS, 16B per lane; LDS dst is wave-uniform base + 16*lane
__device__ __forceinline__ void gl2lds16(const u16* gsrc, u16* ldst) {
    __builtin_amdgcn_global_load_lds(
        (const __attribute__((address_space(1))) void*)gsrc,
        (__attribute__((address_space(3))) void*)ldst, 16, 0, 0);
}

// raw barrier / waitcnt (no compiler-attached vmcnt(0) drain)
#define RAW_BARRIER()   asm volatile("s_barrier" ::: "memory")
#define WAIT_VM(n)      asm volatile("s_waitcnt vmcnt(" #n ")" ::: "memory")
#define SCHED_FENCE()   __builtin_amdgcn_sched_barrier(0)

// ---------------- initial LayerNorm x -> bf16 g (once, pre-loop) -----------
__global__ __launch_bounds__(256) void ln_kernel(const float* __restrict__ x,
    const float* __restrict__ gamma, const float* __restrict__ beta,
    u16* __restrict__ g)
{
    int row = blockIdx.x;
    const float* xr = x + (size_t)row * 768;
    u16* gr = g + (size_t)row * 768;
    int t = threadIdx.x;
    float v0 = xr[t], v1 = xr[t + 256], v2 = xr[t + 512];
    float s = v0 + v1 + v2;
    #pragma unroll
    for (int off = 32; off > 0; off >>= 1) s += __shfl_down(s, off);
    __shared__ float red[8];
    int wid = t >> 6, lane = t & 63;
    if (lane == 0) red[wid] = s;
    __syncthreads();
    if (t == 0) red[0] = (red[0] + red[1] + red[2] + red[3]) * (1.0f / 768.0f);
    __syncthreads();
    float mu = red[0];
    float d0 = v0 - mu, d1 = v1 - mu, d2 = v2 - mu;
    float ss = d0*d0 + d1*d1 + d2*d2;
    #pragma unroll
    for (int off = 32; off > 0; off >>= 1) ss += __shfl_down(ss, off);
    if (lane == 0) red[4 + wid] = ss;
    __syncthreads();
    if (t == 0) red[4] = rsqrtf((red[4] + red[5] + red[6] + red[7]) * (1.0f / 768.0f) + EPS_);
    __syncthreads();
    float rs = red[4];
    gr[t]       = f2bf(gamma[t]       * d0 * rs + beta[t]);
    gr[t + 256] = f2bf(gamma[t + 256] * d1 * rs + beta[t + 256]);
    gr[t + 512] = f2bf(gamma[t + 512] * d2 * rs + beta[t + 512]);
}

// ------- fused: xc += alpha*(P0+P1); g = LN(xc)  (one block per row) --------
__global__ __launch_bounds__(192) void reduce_ln(const u16* __restrict__ part,
    float* __restrict__ xc, const float* __restrict__ gamma,
    const float* __restrict__ beta, u16* __restrict__ g)
{
    int row = blockIdx.x, t = threadIdx.x;
    const u16x4* p0 = (const u16x4*)(part + (size_t)row * 768);
    const u16x4* p1 = (const u16x4*)(part + (size_t)(8192 + row) * 768);
    f32x4* xr = (f32x4*)(xc + (size_t)row * 768);
    f32x4 v = xr[t];
    u16x4 a = p0[t], b = p1[t];
    #pragma unroll
    for (int e = 0; e < 4; ++e) v[e] = fmaf(ALPHA_, bf2f(a[e]) + bf2f(b[e]), v[e]);
    xr[t] = v;
    float s = (v[0] + v[1]) + (v[2] + v[3]);
    #pragma unroll
    for (int off = 32; off > 0; off >>= 1) s += __shfl_down(s, off);
    __shared__ float red[8];
    int wid = t >> 6, lane = t & 63;
    if (lane == 0) red[wid] = s;
    __syncthreads();
    if (t == 0) red[0] = (red[0] + red[1] + red[2]) * (1.0f / 768.0f);
    __syncthreads();
    float mu = red[0];
    f32x4 d;
    #pragma unroll
    for (int e = 0; e < 4; ++e) d[e] = v[e] - mu;
    float ss = (d[0]*d[0] + d[1]*d[1]) + (d[2]*d[2] + d[3]*d[3]);
    #pragma unroll
    for (int off = 32; off > 0; off >>= 1) ss += __shfl_down(ss, off);
    if (lane == 0) red[4 + wid] = ss;
    __syncthreads();
    if (t == 0) red[4] = rsqrtf((red[4] + red[5] + red[6]) * (1.0f / 768.0f) + EPS_);
    __syncthreads();
    float rs = red[4];
    const f32x4 gm = *(const f32x4*)&gamma[t * 4];
    const f32x4 bt = *(const f32x4*)&beta[t * 4];
    u16x4 o;
    #pragma unroll
    for (int e = 0; e < 4; ++e) o[e] = f2bf(fmaf(gm[e], d[e] * rs, bt[e]));
    *(u16x4*)&g[(size_t)row * 768 + t * 4] = o;
}

// ---------------- fp32 -> bf16 convert ----------------
__global__ __launch_bounds__(256) void convert_bf(const float* __restrict__ src,
                                                  u16* __restrict__ dst, int n4)
{
    int i = blockIdx.x * 256 + threadIdx.x;
    if (i < n4) {
        f32x4 v = *(const f32x4*)&src[i * 4];
        u16x4 o;
        #pragma unroll
        for (int e = 0; e < 4; ++e) o[e] = f2bf(v[e]);
        *(u16x4*)&dst[i * 4] = o;
    }
}

// -------- transpose-convert: Wcat [4608x768] f32 -> WcatT [768x4608] bf16 ----
__global__ __launch_bounds__(256) void transpose_bf(const float* __restrict__ Wq,
    const float* __restrict__ Wk, const float* __restrict__ xi, u16* __restrict__ out)
{
    __shared__ float tile[64][65];
    int rb = blockIdx.x * 64, cb = blockIdx.y * 64;
    const float* src;
    if (rb < 768) src = Wq + (size_t)rb * 768;
    else if (rb < 1536) src = Wk + (size_t)(rb - 768) * 768;
    else src = xi + (size_t)(rb - 1536) * 768;
    int t = threadIdx.x;
    #pragma unroll
    for (int it = 0; it < 4; ++it) {
        int r = (t >> 4) + 16 * it;
        f32x4 v = *(const f32x4*)&src[(size_t)r * 768 + cb + (t & 15) * 4];
        #pragma unroll
        for (int e = 0; e < 4; ++e) tile[r][(t & 15) * 4 + e] = v[e];
    }
    __syncthreads();
    #pragma unroll
    for (int it = 0; it < 4; ++it) {
        int cl = (t >> 4) + 16 * it;
        u16x4 o;
        #pragma unroll
        for (int e = 0; e < 4; ++e) o[e] = f2bf(tile[(t & 15) * 4 + e][cl]);
        *(u16x4*)&out[(size_t)(cb + cl) * 4608 + rb + (t & 15) * 4] = o;
    }
}

// ======== 128x128 TWO-phase GEMM core, 2 BLOCKS/CU ==========================
// 8 waves 2Mx4N, per-wave 64x32 out (acc[4][2] = 32 AGPR), BK=64,
// 2 LDS buffers x 32 KB = 64 KB -> 2 blocks/CU (16 waves/CU, 4/SIMD via
// __launch_bounds__(512,4)). Co-resident independent blocks absorb the
// barrier/vmcnt convoy (m97/m114 mechanism) while the counted-vmcnt keeps
// loads 2 tiles ahead. Phase A: {read A-frags 0-1 + ALL B; stage A(t+1)x2;
// barrier; 8 MFMA; barrier}. Phase B: {read A-frags 2-3; stage B(t+2)x2 into
// freed B-region; barrier; 8 MFMA; vmcnt(2); barrier}. Drain: outstanding at
// tile end = B(t+1)2+A(t+1)2+B(t+2)2 = 6 -> vmcnt(2) keeps exactly B(t+2).

// ---------------- fused fwd GEMM: [qk | relu-mid] = g . Wcat^T --------------
// Grid 2304 = 8 XCD x (36 n x 8 m); per-XCD A-slab 1024 rows (1.5 MB) L2-hot.
__global__ __launch_bounds__(512, 4) void gemm_fwd(
    const u16* __restrict__ A,      // g [8192 x 768]
    const u16* __restrict__ Bt,     // Wcat rows [4608 x 768] (Wq|Wk|xi)
    u16* __restrict__ qkb, u16* __restrict__ qkT, u16* __restrict__ midb)
{
    // per buffer (16384 u16 = 32 KB): A [0,8192) 128r x 64k, B [8192,16384)
    __shared__ __align__(16) u16 S[2][16384];
    const int t = threadIdx.x, w = t >> 6, l = t & 63, g = l >> 4, cid = l & 15;
    const int lr = l & 15, lc = l >> 4;
    const int wm = w >> 2, wn = w & 3;
    const int flat = blockIdx.x;
    const int xcd = flat & 7, slot = flat >> 3;   // 288 slots per XCD
    const int nid = slot >> 3, mloc = slot & 7;
    const int bm = (xcd * 8 + mloc) * 128;        // 64 m-tiles
    const int bn = nid * 128;                     // 36 n-tiles
    const int NT = 12;                            // K = 768 = 12 x 64

    // staging: wave w owns 16-row frag w of A and of B, both k-halves (j)
    const u16* aS[2]; int ldA[2];
    const u16* bS[2]; int ldB[2];
    #pragma unroll
    for (int j = 0; j < 2; ++j) {
        aS[j] = A  + (size_t)(bm + 16 * w + lr) * 768 + 32 * j + 8 * lc;
        ldA[j] = (2 * w + j) * 512 + l * 8;
        bS[j] = Bt + (size_t)(bn + 16 * w + lr) * 768 + 32 * j + 8 * lc;
        ldB[j] = 8192 + (2 * w + j) * 512 + l * 8;
    }

    f32x4 acc[4][2] = {};
    bf16x8 afr[2][2], bfr[2][2];

    // prologue: B(0)x2, A(0)x2 -> buf0; B(1)x2 -> buf1; wait leaves B(1)
    gl2lds16(bS[0], &S[0][ldB[0]]); gl2lds16(bS[1], &S[0][ldB[1]]);
    gl2lds16(aS[0], &S[0][ldA[0]]); gl2lds16(aS[1], &S[0][ldA[1]]);
    gl2lds16(bS[0] + 64, &S[1][ldB[0]]); gl2lds16(bS[1] + 64, &S[1][ldB[1]]);
    WAIT_VM(2); RAW_BARRIER();

    #pragma unroll 1
    for (int tt = 0; tt < NT; ++tt) {
        const int bf = tt & 1, ob = bf ^ 1;
        const u16* Sa = &S[bf][0];
        const u16* Sb = &S[bf][8192];
        // chunk c=(rf*2+kh): offset c*512 + l*8
        #define LDS_A(ii, hh) (*(const bf16x8*)&Sa[(((wm * 4 + (ii)) * 2 + (hh)) * 512) + l * 8])
        #define LDS_B(jj, hh) (*(const bf16x8*)&Sb[(((wn * 2 + (jj)) * 2 + (hh)) * 512) + l * 8])
        #define MM(ii, jj) { \
            acc[ii][jj] = MFMA(afr[(ii) & 1][0], bfr[jj][0], acc[ii][jj], 0, 0, 0); \
            acc[ii][jj] = MFMA(afr[(ii) & 1][1], bfr[jj][1], acc[ii][jj], 0, 0, 0); }
        // Phase A: read A frags 0-1 + ALL B; stage A(t+1) x2
        #pragma unroll
        for (int i = 0; i < 2; ++i) { afr[i][0] = LDS_A(i, 0); afr[i][1] = LDS_A(i, 1); }
        #pragma unroll
        for (int j = 0; j < 2; ++j) { bfr[j][0] = LDS_B(j, 0); bfr[j][1] = LDS_B(j, 1); }
        if (tt + 1 < NT) { gl2lds16(aS[0] + 64 * (tt + 1), &S[ob][ldA[0]]);
                           gl2lds16(aS[1] + 64 * (tt + 1), &S[ob][ldA[1]]); }
        RAW_BARRIER();
        __builtin_amdgcn_s_setprio(1);
        MM(0, 0); MM(0, 1); MM(1, 0); MM(1, 1);
        __builtin_amdgcn_s_setprio(0);
        SCHED_FENCE(); RAW_BARRIER();
        // Phase B: read A frags 2-3; stage B(t+2) into freed B-region
        #pragma unroll
        for (int i = 0; i < 2; ++i) { afr[i][0] = LDS_A(2 + i, 0); afr[i][1] = LDS_A(2 + i, 1); }
        if (tt + 2 < NT) { gl2lds16(bS[0] + 64 * (tt + 2), &S[bf][ldB[0]]);
                           gl2lds16(bS[1] + 64 * (tt + 2), &S[bf][ldB[1]]); }
        RAW_BARRIER();
        __builtin_amdgcn_s_setprio(1);
        MM(2, 0); MM(2, 1); MM(3, 0); MM(3, 1);
        __builtin_amdgcn_s_setprio(0);
        SCHED_FENCE();
        if (tt < NT - 2)       { WAIT_VM(2); }
        else if (tt == NT - 2) { WAIT_VM(0); }
        RAW_BARRIER();
        #undef LDS_A
        #undef LDS_B
        #undef MM
    }

    if (bn < 1536) {
        int bidx = bm >> 10;
        #pragma unroll
        for (int i = 0; i < 4; ++i) {
            int tok = bm + wm * 64 + 16 * i + 4 * g;
            #pragma unroll
            for (int j = 0; j < 2; ++j) {
                int col = bn + wn * 32 + 16 * j + cid;
                int sel = col >= 768 ? 1 : 0;
                int cc = col - 768 * sel;
                int hh = cc >> 6, yy = cc & 63;
                u16x4 tv;
                #pragma unroll
                for (int r = 0; r < 4; ++r) {
                    u16 bv = f2bf(acc[i][j][r]);
                    tv[r] = bv;
                    qkb[(size_t)(tok + r) * 1536 + col] = bv;
                }
                *(u16x4*)&qkT[((((size_t)bidx * 12 + hh) * 2 + sel) * 64 + yy) * 1024 + (tok & 1023)] = tv;
            }
        }
    } else {
        #pragma unroll
        for (int i = 0; i < 4; ++i)
            #pragma unroll
            for (int r = 0; r < 4; ++r) {
                size_t row = bm + wm * 64 + 16 * i + 4 * g + r;
                #pragma unroll
                for (int j = 0; j < 2; ++j) {
                    int col = bn + wn * 32 + 16 * j + cid;
                    midb[row * 4608 + col] = f2bf(fmaxf(acc[i][j][r], 0.0f));
                }
            }
    }
}

// ------- update GEMM: part[z] = mid . WcatT (K-half z), bf16 partials -------
// Grid 768 = 8 XCD x (2 z x 6 n x 8 m). K-half = 2304 = 36 x 64.
__global__ __launch_bounds__(512, 4) void gemm_upd(
    const u16* __restrict__ A,      // mid [8192 x 4608]
    const u16* __restrict__ Bt,     // WcatT [768 x 4608]
    u16* __restrict__ part)         // [2][8192][768] bf16
{
    __shared__ __align__(16) u16 S[2][16384];
    const int t = threadIdx.x, w = t >> 6, l = t & 63, g = l >> 4, cid = l & 15;
    const int lr = l & 15, lc = l >> 4;
    const int wm = w >> 2, wn = w & 3;
    const int flat = blockIdx.x;
    const int xcd = flat & 7, slot = flat >> 3;   // 96 slots per XCD
    const int z = slot / 48, rem = slot % 48;     // z-outer (B z-slice L2-hot)
    const int nid = rem >> 3, mloc = rem & 7;
    const int bm = (xcd * 8 + mloc) * 128, bn = nid * 128;
    const int kbeg = z * 2304;
    const int NT = 36;                            // 2304 = 36 x 64
    u16* out = part + (size_t)z * 8192 * 768;

    const u16* aS[2]; int ldA[2];
    const u16* bS[2]; int ldB[2];
    #pragma unroll
    for (int j = 0; j < 2; ++j) {
        aS[j] = A  + (size_t)(bm + 16 * w + lr) * 4608 + kbeg + 32 * j + 8 * lc;
        ldA[j] = (2 * w + j) * 512 + l * 8;
        bS[j] = Bt + (size_t)(bn + 16 * w + lr) * 4608 + kbeg + 32 * j + 8 * lc;
        ldB[j] = 8192 + (2 * w + j) * 512 + l * 8;
    }

    f32x4 acc[4][2] = {};
    bf16x8 afr[2][2], bfr[2][2];

    gl2lds16(bS[0], &S[0][ldB[0]]); gl2lds16(bS[1], &S[0][ldB[1]]);
    gl2lds16(aS[0], &S[0][ldA[0]]); gl2lds16(aS[1], &S[0][ldA[1]]);
    gl2lds16(bS[0] + 64, &S[1][ldB[0]]); gl2lds16(bS[1] + 64, &S[1][ldB[1]]);
    WAIT_VM(2); RAW_BARRIER();

    #pragma unroll 1
    for (int tt = 0; tt < NT; ++tt) {
        const int bf = tt & 1, ob = bf ^ 1;
        const u16* Sa = &S[bf][0];
        const u16* Sb = &S[bf][8192];
        #define LDS_A(ii, hh) (*(const bf16x8*)&Sa[(((wm * 4 + (ii)) * 2 + (hh)) * 512) + l * 8])
        #define LDS_B(jj, hh) (*(const bf16x8*)&Sb[(((wn * 2 + (jj)) * 2 + (hh)) * 512) + l * 8])
        #define MM(ii, jj) { \
            acc[ii][jj] = MFMA(afr[(ii) & 1][0], bfr[jj][0], acc[ii][jj], 0, 0, 0); \
            acc[ii][jj] = MFMA(afr[(ii) & 1][1], bfr[jj][1], acc[ii][jj], 0, 0, 0); }
        #pragma unroll
        for (int i = 0; i < 2; ++i) { afr[i][0] = LDS_A(i, 0); afr[i][1] = LDS_A(i, 1); }
        #pragma unroll
        for (int j = 0; j < 2; ++j) { bfr[j][0] = LDS_B(j, 0); bfr[j][1] = LDS_B(j, 1); }
        if (tt + 1 < NT) { gl2lds16(aS[0] + 64 * (tt + 1), &S[ob][ldA[0]]);
                           gl2lds16(aS[1] + 64 * (tt + 1), &S[ob][ldA[1]]); }
        RAW_BARRIER();
        __builtin_amdgcn_s_setprio(1);
        MM(0, 0); MM(0, 1); MM(1, 0); MM(1, 1);
        __builtin_amdgcn_s_setprio(0);
        SCHED_FENCE(); RAW_BARRIER();
        #pragma unroll
        for (int i = 0; i < 2; ++i) { afr[i][0] = LDS_A(2 + i, 0); afr[i][1] = LDS_A(2 + i, 1); }
        if (tt + 2 < NT) { gl2lds16(bS[0] + 64 * (tt + 2), &S[bf][ldB[0]]);
                           gl2lds16(bS[1] + 64 * (tt + 2), &S[bf][ldB[1]]); }
        RAW_BARRIER();
        __builtin_amdgcn_s_setprio(1);
        MM(2, 0); MM(2, 1); MM(3, 0); MM(3, 1);
        __builtin_amdgcn_s_setprio(0);
        SCHED_FENCE();
        if (tt < NT - 2)       { WAIT_VM(2); }
        else if (tt == NT - 2) { WAIT_VM(0); }
        RAW_BARRIER();
        #undef LDS_A
        #undef LDS_B
        #undef MM
    }

    #pragma unroll
    for (int i = 0; i < 4; ++i)
        #pragma unroll
        for (int r = 0; r < 4; ++r) {
            size_t row = bm + wm * 64 + 16 * i + 4 * g + r;
            #pragma unroll
            for (int j = 0; j < 2; ++j)
                out[row * 768 + bn + wn * 32 + 16 * j + cid] = f2bf(acc[i][j][r]);
        }
}

// ---------------- dq: flash pass over k, 128-q tile, computes L and Aq -------
__global__ __launch_bounds__(256) void dq_kernel(const u16* __restrict__ qk,
    const u16* __restrict__ qkT, float* __restrict__ L, u16* __restrict__ mid)
{
    const int flat = blockIdx.x;
    const int xcd = flat & 7, slot = flat >> 3;       // 96 slots per XCD
    const int bh = xcd * 12 + slot / 8;               // 12 bh per XCD
    const int q0 = (slot % 8) << 7;
    const int b = bh / H_, h = bh % H_;
    const u16* qbase = qk + (size_t)b * 1024 * 1536 + h * 64;
    const u16* kbase = qbase + 768;
    const u16* ktg = qkT + ((size_t)bh * 2 + 1) * 64 * 1024;   // K^T [y][1024]
    __shared__ __align__(16) u16 KB[2][8192];   // per buf: Kn [0,4096) | Kt [4096,8192)
    __shared__ __align__(16) u16 Ps[8192];
    const int t = threadIdx.x, w = t >> 6, l = t & 63, g = l >> 4, cid = l & 15;
    const int lr = l & 15, lc = l >> 4;

    #pragma unroll
    for (int h2 = 0; h2 < 2; ++h2)
        #pragma unroll
        for (int ch = 0; ch < 2; ++ch)
            gl2lds16(&qbase[(size_t)(q0 + 32 * w + 16 * h2 + lr) * 1536 + 32 * ch + 8 * lc],
                     &KB[0][(128 * (2 * w + h2) + 64 * ch + l) * 8]);
    __syncthreads();
    bf16x8 QF[2][2];
    #pragma unroll
    for (int jj = 0; jj < 2; ++jj)
        #pragma unroll
        for (int hh = 0; hh < 2; ++hh)
            QF[jj][hh] = *(const bf16x8*)&KB[0][(128 * (2 * w + jj) + 64 * hh + l) * 8];
    __syncthreads();   // all QF reads done before KB[0] is restaged

    auto stageK = [&](int buf, int kt) {   // 4 gl2lds per wave
        #pragma unroll
        for (int ch = 0; ch < 2; ++ch) {
            gl2lds16(&kbase[(size_t)(kt * 64 + 16 * w + lr) * 1536 + 32 * ch + 8 * lc],
                     &KB[buf][(128 * w + 64 * ch + l) * 8]);
            gl2lds16(&ktg[(size_t)(16 * w + lr) * 1024 + kt * 64 + 32 * ch + 8 * lc],
                     &KB[buf][4096 + (128 * w + 64 * ch + l) * 8]);
        }
    };

    f32x4 acc[2][4] = {};
    float lrun[2] = {0.0f, 0.0f};

    stageK(0, 0); stageK(1, 1);
    #pragma unroll 1
    for (int kt = 0; kt < 16; ++kt) {
        if (kt == 15) { WAIT_VM(0); } else { WAIT_VM(4); }
        RAW_BARRIER();
        const int buf = kt & 1;
        const u16* Kn = &KB[buf][0];
        const u16* Kt = &KB[buf][4096];
        f32x4 s[4][2];
        #pragma unroll
        for (int i = 0; i < 4; ++i) {
            bf16x8 a0 = *(const bf16x8*)&Kn[(128 * i + l) * 8];
            bf16x8 a1 = *(const bf16x8*)&Kn[(128 * i + 64 + l) * 8];
            #pragma unroll
            for (int jj = 0; jj < 2; ++jj) {
                f32x4 z = {0.f, 0.f, 0.f, 0.f};
                z = MFMA(a0, QF[jj][0], z, 0, 0, 0);
                z = MFMA(a1, QF[jj][1], z, 0, 0, 0);
                s[i][jj] = z;
            }
        }
        #pragma unroll
        for (int jj = 0; jj < 2; ++jj) {
            float psum = 0.0f;
            #pragma unroll
            for (int i = 0; i < 4; ++i) {
                u16x4 pv;
                #pragma unroll
                for (int r = 0; r < 4; ++r) {
                    float p = EXP2F(s[i][jj][r] * B2L_);
                    psum += p;
                    pv[r] = f2bf_rz(p);
                }
                *(u16x4*)&Ps[(128 * (2 * w + jj) + 32 * i + 16 * (g >> 1) + cid) * 8 + 4 * (g & 1)] = pv;
            }
            psum += __shfl_xor(psum, 16);
            psum += __shfl_xor(psum, 32);
            lrun[jj] += psum;
        }
        #pragma unroll
        for (int jj = 0; jj < 2; ++jj) {
            bf16x8 p0 = *(const bf16x8*)&Ps[(128 * (2 * w + jj) + l) * 8];
            bf16x8 p1 = *(const bf16x8*)&Ps[(128 * (2 * w + jj) + 64 + l) * 8];
            #pragma unroll
            for (int j = 0; j < 4; ++j) {
                acc[jj][j] = MFMA(p0, *(const bf16x8*)&Kt[(128 * j + l) * 8], acc[jj][j], 0, 0, 0);
                acc[jj][j] = MFMA(p1, *(const bf16x8*)&Kt[(128 * j + 64 + l) * 8], acc[jj][j], 0, 0, 0);
            }
        }
        RAW_BARRIER();
        if (kt + 2 < 16) stageK(buf, kt + 2);
    }
    #pragma unroll
    for (int jj = 0; jj < 2; ++jj) {
        if (g == 0)
            L[(size_t)bh * 1024 + q0 + 32 * w + 16 * jj + cid] = __logf(lrun[jj]);
        float linv = 1.0f / lrun[jj];
        #pragma unroll
        for (int r = 0; r < 4; ++r) {
            float fr = __shfl(linv, 4 * g + r);
            int row = q0 + 32 * w + 16 * jj + 4 * g + r;
            #pragma unroll
            for (int j = 0; j < 4; ++j)
                mid[(size_t)(b * 1024 + row) * 4608 + h * 64 + 16 * j + cid] = f2bf(acc[jj][j][r] * fr);
        }
    }
}

// ---------------- dk: Ak[k] = sum_q exp(beta*S - L[q]) q, 128-k tile --------
__global__ __launch_bounds__(256) void dk_kernel(const u16* __restrict__ qk,
    const u16* __restrict__ qkT, const float* __restrict__ L, u16* __restrict__ mid)
{
    const int flat = blockIdx.x;
    const int xcd = flat & 7, slot = flat >> 3;
    const int bh = xcd * 12 + slot / 8;
    const int k0 = (slot % 8) << 7;
    const int b = bh / H_, h = bh % H_;
    const u16* qbase = qk + (size_t)b * 1024 * 1536 + h * 64;
    const u16* kbase = qbase + 768;
    const u16* qtg = qkT + ((size_t)bh * 2 + 0) * 64 * 1024;   // Q^T [y][1024]
    __shared__ __align__(16) u16 KB[2][8192];   // per buf: Qn [0,4096) | Qt [4096,8192)
    __shared__ __align__(16) u16 Ps[8192];
    const int t = threadIdx.x, w = t >> 6, l = t & 63, g = l >> 4, cid = l & 15;
    const int lr = l & 15, lc = l >> 4;

    #pragma unroll
    for (int h2 = 0; h2 < 2; ++h2)
        #pragma unroll
        for (int ch = 0; ch < 2; ++ch)
            gl2lds16(&kbase[(size_t)(k0 + 32 * w + 16 * h2 + lr) * 1536 + 32 * ch + 8 * lc],
                     &KB[0][(128 * (2 * w + h2) + 64 * ch + l) * 8]);
    __syncthreads();
    bf16x8 KF[2][2];
    #pragma unroll
    for (int jj = 0; jj < 2; ++jj)
        #pragma unroll
        for (int hh = 0; hh < 2; ++hh)
            KF[jj][hh] = *(const bf16x8*)&KB[0][(128 * (2 * w + jj) + 64 * hh + l) * 8];
    __syncthreads();

    auto stageQ = [&](int buf, int qt) {   // 4 gl2lds per wave
        #pragma unroll
        for (int ch = 0; ch < 2; ++ch) {
            gl2lds16(&qbase[(size_t)(qt * 64 + 16 * w + lr) * 1536 + 32 * ch + 8 * lc],
                     &KB[buf][(128 * w + 64 * ch + l) * 8]);
            gl2lds16(&qtg[(size_t)(16 * w + lr) * 1024 + qt * 64 + 32 * ch + 8 * lc],
                     &KB[buf][4096 + (128 * w + 64 * ch + l) * 8]);
        }
    };

    f32x4 acc[2][4] = {};
    stageQ(0, 0); stageQ(1, 1);
    #pragma unroll 1
    for (int qt = 0; qt < 16; ++qt) {
        if (qt == 15) { WAIT_VM(0); } else { WAIT_VM(4); }
        RAW_BARRIER();
        const int buf = qt & 1;
        const u16* Qn = &KB[buf][0];
        const u16* Qt = &KB[buf][4096];
        #pragma unroll
        for (int i = 0; i < 4; ++i) {
            bf16x8 a0 = *(const bf16x8*)&Qn[(128 * i + l) * 8];
            bf16x8 a1 = *(const bf16x8*)&Qn[(128 * i + 64 + l) * 8];
            f32x4 lv = *(const f32x4*)&L[(size_t)bh * 1024 + qt * 64 + 16 * i + 4 * g];
            f32x4 lv2;
            #pragma unroll
            for (int r = 0; r < 4; ++r) lv2[r] = lv[r] * L2E_;
            #pragma unroll
            for (int jj = 0; jj < 2; ++jj) {
                f32x4 z = {0.f, 0.f, 0.f, 0.f};
                z = MFMA(a0, KF[jj][0], z, 0, 0, 0);
                z = MFMA(a1, KF[jj][1], z, 0, 0, 0);
                u16x4 pv;
                #pragma unroll
                for (int r = 0; r < 4; ++r)
                    pv[r] = f2bf_rz(EXP2F(fmaf(z[r], B2L_, -lv2[r])));
                *(u16x4*)&Ps[(128 * (2 * w + jj) + 32 * i + 16 * (g >> 1) + cid) * 8 + 4 * (g & 1)] = pv;
            }
        }
        #pragma unroll
        for (int jj = 0; jj < 2; ++jj) {
            bf16x8 p0 = *(const bf16x8*)&Ps[(128 * (2 * w + jj) + l) * 8];
            bf16x8 p1 = *(const bf16x8*)&Ps[(128 * (2 * w + jj) + 64 + l) * 8];
            #pragma unroll
            for (int j = 0; j < 4; ++j) {
                acc[jj][j] = MFMA(p0, *(const bf16x8*)&Qt[(128 * j + l) * 8], acc[jj][j], 0, 0, 0);
                acc[jj][j] = MFMA(p1, *(const bf16x8*)&Qt[(128 * j + 64 + l) * 8], acc[jj][j], 0, 0, 0);
            }
        }
        RAW_BARRIER();
        if (qt + 2 < 16) stageQ(buf, qt + 2);
    }
    #pragma unroll
    for (int jj = 0; jj < 2; ++jj)
        #pragma unroll
        for (int r = 0; r < 4; ++r) {
            int row = k0 + 32 * w + 16 * jj + 4 * g + r;
            #pragma unroll
            for (int j = 0; j < 4; ++j)
                mid[(size_t)(b * 1024 + row) * 4608 + 768 + h * 64 + 16 * j + cid] = f2bf(acc[jj][j][r]);
        }
}

// ---------------------------------------------------------------------------
extern "C" void kernel_launch(void* const* d_in, const int* in_sizes, int n_in,
                              void* d_out, int out_size, void* d_ws, size_t ws_size,
                              hipStream_t stream)
{
    const float* x     = (const float*)d_in[0];
    const float* gamma = (const float*)d_in[1];
    const float* betap = (const float*)d_in[2];
    const float* Wq    = (const float*)d_in[3];
    const float* Wk    = (const float*)d_in[4];
    const float* xi    = (const float*)d_in[5];
    float* xc = (float*)d_out;

    char* p = (char*)d_ws;
    u16* wcat_bf  = (u16*)p; p += (size_t)4608 * 768 * 2;   // [Wq;Wk;xi] rows
    u16* wcatT_bf = (u16*)p; p += (size_t)768 * 4608 * 2;
    u16* g_bf     = (u16*)p; p += (size_t)NTOK * 768 * 2;
    u16* qk_bf    = (u16*)p; p += (size_t)NTOK * 1536 * 2;
    u16* qkT_bf   = (u16*)p; p += (size_t)96 * 2 * 64 * 1024 * 2;
    u16* mid_bf   = (u16*)p; p += (size_t)NTOK * 4608 * 2;
    float* L      = (float*)p; p += (size_t)96 * 1024 * 4;
    // part[2][8192][768] bf16 = 25.17 MB ALIASES qk_bf (25.17 MB exactly):
    // qk is dead once dq/dk complete; part is consumed by reduce_ln before
    // the next step's gemm_fwd rewrites qk.
    u16* part = qk_bf;
    (void)ws_size; (void)in_sizes; (void)n_in; (void)out_size;

    hipMemcpyAsync(xc, x, (size_t)NTOK * 768 * 4, hipMemcpyDeviceToDevice, stream);

    convert_bf<<<576, 256, 0, stream>>>(Wq, wcat_bf, 147456);
    convert_bf<<<576, 256, 0, stream>>>(Wk, wcat_bf + 768 * 768, 147456);
    convert_bf<<<2304, 256, 0, stream>>>(xi, wcat_bf + 2 * 768 * 768, 589824);
    transpose_bf<<<dim3(72, 12), 256, 0, stream>>>(Wq, Wk, xi, wcatT_bf);

    // g_0 = LN(x)
    ln_kernel<<<NTOK, 256, 0, stream>>>(x, gamma, betap, g_bf);

    for (int step = 0; step < STEPS_; ++step) {
        // fused: qk (+qkT) and relu-mid in one N=4608 GEMM
        // (128x128, 2-phase counted-vmcnt, 2 blocks/CU)
        gemm_fwd<<<2304, 512, 0, stream>>>(
            g_bf, wcat_bf, qk_bf, qkT_bf, mid_bf);
        // Aq (+L), Ak  (XCD-swizzled, ping-pong staged)
        dq_kernel<<<768, 256, 0, stream>>>(qk_bf, qkT_bf, L, mid_bf);
        dk_kernel<<<768, 256, 0, stream>>>(qk_bf, qkT_bf, L, mid_bf);
        // part[z] = mid . Wcat (2 K-halves, 128x128, 2 blocks/CU)
        gemm_upd<<<768, 512, 0, stream>>>(mid_bf, wcatT_bf, part);
        // xc += alpha*(P0+P1); g = LN(xc)   (fused)
        reduce_ln<<<NTOK, 192, 0, stream>>>(part, xc, gamma, betap, g_bf);
    }
}

// Round 11
// 3024.000 us; speedup vs baseline: 1.2485x; 1.2485x over previous
//
#include <hip/hip_runtime.h>
#include <math.h>

#define H_ 12
#define STEPS_ 12
#define ALPHA_ 0.1f
#define EPS_ 1e-5f
#define BETA_ 0.125f          // 1/sqrt(64)
#define B2L_ 0.1803368801111204f   // BETA_ * log2(e)
#define L2E_ 1.4426950408889634f
#define NTOK 8192
#define COLP 194              // padded LDS cols for epilogue transpose

typedef unsigned short u16;
typedef __attribute__((ext_vector_type(8))) u16 u16x8;
typedef __attribute__((ext_vector_type(4))) u16 u16x4;
typedef __attribute__((ext_vector_type(4))) float f32x4;
typedef __attribute__((ext_vector_type(8))) __bf16 bf16x8;

#define MFMA __builtin_amdgcn_mfma_f32_16x16x32_bf16
#define EXP2F(x) __builtin_amdgcn_exp2f(x)

__device__ __forceinline__ u16 f2bf(float x) {
    unsigned u = __float_as_uint(x);
    u += 0x7FFFu + ((u >> 16) & 1u);
    return (u16)(u >> 16);
}
__device__ __forceinline__ float bf2f(u16 u) {
    return __uint_as_float(((unsigned)u) << 16);
}
// truncation pack (1 VALU) for positive P values — ≤0.4% rel err, RTZ
__device__ __forceinline__ u16 f2bf_rz(float x) {
    return (u16)(__float_as_uint(x) >> 16);
}

// async global->LDS, 16B per lane; LDS dst is wave-uniform base + 16*lane
__device__ __forceinline__ void gl2lds16(const u16* gsrc, u16* ldst) {
    __builtin_amdgcn_global_load_lds(
        (const __attribute__((address_space(1))) void*)gsrc,
        (__attribute__((address_space(3))) void*)ldst, 16, 0, 0);
}

// raw barrier / waitcnt (no compiler-attached vmcnt(0) drain)
#define RAW_BARRIER()   asm volatile("s_barrier" ::: "memory")
#define WAIT_VM(n)      asm volatile("s_waitcnt vmcnt(" #n ")" ::: "memory")
#define SCHED_FENCE()   __builtin_amdgcn_sched_barrier(0)

// ---------------- initial LayerNorm x -> bf16 g (once, pre-loop) -----------
__global__ __launch_bounds__(256) void ln_kernel(const float* __restrict__ x,
    const float* __restrict__ gamma, const float* __restrict__ beta,
    u16* __restrict__ g)
{
    int row = blockIdx.x;
    const float* xr = x + (size_t)row * 768;
    u16* gr = g + (size_t)row * 768;
    int t = threadIdx.x;
    float v0 = xr[t], v1 = xr[t + 256], v2 = xr[t + 512];
    float s = v0 + v1 + v2;
    #pragma unroll
    for (int off = 32; off > 0; off >>= 1) s += __shfl_down(s, off);
    __shared__ float red[8];
    int wid = t >> 6, lane = t & 63;
    if (lane == 0) red[wid] = s;
    __syncthreads();
    if (t == 0) red[0] = (red[0] + red[1] + red[2] + red[3]) * (1.0f / 768.0f);
    __syncthreads();
    float mu = red[0];
    float d0 = v0 - mu, d1 = v1 - mu, d2 = v2 - mu;
    float ss = d0*d0 + d1*d1 + d2*d2;
    #pragma unroll
    for (int off = 32; off > 0; off >>= 1) ss += __shfl_down(ss, off);
    if (lane == 0) red[4 + wid] = ss;
    __syncthreads();
    if (t == 0) red[4] = rsqrtf((red[4] + red[5] + red[6] + red[7]) * (1.0f / 768.0f) + EPS_);
    __syncthreads();
    float rs = red[4];
    gr[t]       = f2bf(gamma[t]       * d0 * rs + beta[t]);
    gr[t + 256] = f2bf(gamma[t + 256] * d1 * rs + beta[t + 256]);
    gr[t + 512] = f2bf(gamma[t + 512] * d2 * rs + beta[t + 512]);
}

// ------- fused: xc += alpha*(P0+P1); g = LN(xc)  (one block per row) --------
__global__ __launch_bounds__(192) void reduce_ln(const u16* __restrict__ part,
    float* __restrict__ xc, const float* __restrict__ gamma,
    const float* __restrict__ beta, u16* __restrict__ g)
{
    int row = blockIdx.x, t = threadIdx.x;
    const u16x4* p0 = (const u16x4*)(part + (size_t)row * 768);
    const u16x4* p1 = (const u16x4*)(part + (size_t)(8192 + row) * 768);
    f32x4* xr = (f32x4*)(xc + (size_t)row * 768);
    f32x4 v = xr[t];
    u16x4 a = p0[t], b = p1[t];
    #pragma unroll
    for (int e = 0; e < 4; ++e) v[e] = fmaf(ALPHA_, bf2f(a[e]) + bf2f(b[e]), v[e]);
    xr[t] = v;
    float s = (v[0] + v[1]) + (v[2] + v[3]);
    #pragma unroll
    for (int off = 32; off > 0; off >>= 1) s += __shfl_down(s, off);
    __shared__ float red[8];
    int wid = t >> 6, lane = t & 63;
    if (lane == 0) red[wid] = s;
    __syncthreads();
    if (t == 0) red[0] = (red[0] + red[1] + red[2]) * (1.0f / 768.0f);
    __syncthreads();
    float mu = red[0];
    f32x4 d;
    #pragma unroll
    for (int e = 0; e < 4; ++e) d[e] = v[e] - mu;
    float ss = (d[0]*d[0] + d[1]*d[1]) + (d[2]*d[2] + d[3]*d[3]);
    #pragma unroll
    for (int off = 32; off > 0; off >>= 1) ss += __shfl_down(ss, off);
    if (lane == 0) red[4 + wid] = ss;
    __syncthreads();
    if (t == 0) red[4] = rsqrtf((red[4] + red[5] + red[6]) * (1.0f / 768.0f) + EPS_);
    __syncthreads();
    float rs = red[4];
    const f32x4 gm = *(const f32x4*)&gamma[t * 4];
    const f32x4 bt = *(const f32x4*)&beta[t * 4];
    u16x4 o;
    #pragma unroll
    for (int e = 0; e < 4; ++e) o[e] = f2bf(fmaf(gm[e], d[e] * rs, bt[e]));
    *(u16x4*)&g[(size_t)row * 768 + t * 4] = o;
}

// ---------------- fp32 -> bf16 convert ----------------
__global__ __launch_bounds__(256) void convert_bf(const float* __restrict__ src,
                                                  u16* __restrict__ dst, int n4)
{
    int i = blockIdx.x * 256 + threadIdx.x;
    if (i < n4) {
        f32x4 v = *(const f32x4*)&src[i * 4];
        u16x4 o;
        #pragma unroll
        for (int e = 0; e < 4; ++e) o[e] = f2bf(v[e]);
        *(u16x4*)&dst[i * 4] = o;
    }
}

// -------- transpose-convert: Wcat [4608x768] f32 -> WcatT [768x4608] bf16 ----
__global__ __launch_bounds__(256) void transpose_bf(const float* __restrict__ Wq,
    const float* __restrict__ Wk, const float* __restrict__ xi, u16* __restrict__ out)
{
    __shared__ float tile[64][65];
    int rb = blockIdx.x * 64, cb = blockIdx.y * 64;
    const float* src;
    if (rb < 768) src = Wq + (size_t)rb * 768;
    else if (rb < 1536) src = Wk + (size_t)(rb - 768) * 768;
    else src = xi + (size_t)(rb - 1536) * 768;
    int t = threadIdx.x;
    #pragma unroll
    for (int it = 0; it < 4; ++it) {
        int r = (t >> 4) + 16 * it;
        f32x4 v = *(const f32x4*)&src[(size_t)r * 768 + cb + (t & 15) * 4];
        #pragma unroll
        for (int e = 0; e < 4; ++e) tile[r][(t & 15) * 4 + e] = v[e];
    }
    __syncthreads();
    #pragma unroll
    for (int it = 0; it < 4; ++it) {
        int cl = (t >> 4) + 16 * it;
        u16x4 o;
        #pragma unroll
        for (int e = 0; e < 4; ++e) o[e] = f2bf(tile[(t & 15) * 4 + e][cl]);
        *(u16x4*)&out[(size_t)(cb + cl) * 4608 + rb + (t & 15) * 4] = o;
    }
}

// ======== 256x192 TWO-phase GEMM core (R8, best) + LDS-transposed epilogue ==
// Main loop byte-identical to R8 (3035us verified). Epilogue: scalar bf16
// stores (96/thread) replaced by LDS roundtrip (Ct[256][COLP=194], ~2-way-free
// banks) + 12 coalesced u16x8 global stores/thread. qkT keeps direct quads.

// ---------------- fused fwd GEMM: [qk | relu-mid] = g . Wcat^T --------------
// Grid 768 = 8 XCD x (24 n x 4 m).
__global__ __launch_bounds__(512) void gemm_fwd(
    const u16* __restrict__ A,      // g [8192 x 768]
    const u16* __restrict__ Bt,     // Wcat rows [4608 x 768] (Wq|Wk|xi)
    u16* __restrict__ qkb, u16* __restrict__ qkT, u16* __restrict__ midb)
{
    // per buffer (28672 u16 = 56 KB): A [0,16384) 256rx64k, B [16384,28672) 192rx64k
    __shared__ __align__(16) u16 S[2][28672];
    const int t = threadIdx.x, w = t >> 6, l = t & 63, g = l >> 4, cid = l & 15;
    const int lr = l & 15, lc = l >> 4;
    const int wm = w >> 2, wn = w & 3;
    const int flat = blockIdx.x;
    const int xcd = flat & 7, slot = flat >> 3;   // 96 slots per XCD
    const int nid = slot >> 2, mloc = slot & 3;
    const int bm = (xcd * 4 + mloc) * 256;        // 32 m-tiles
    const int bn = nid * 192;                     // 24 n-tiles
    const int NT = 12;                            // K = 768 = 12 x 64

    // staging: A chunks j=0..3 (rf=2w+(j>>1), kh=j&1); B chunks j=0..2 (c=3w+j)
    const u16* aS[4]; int ldA[4];
    #pragma unroll
    for (int j = 0; j < 4; ++j) {
        int rf = 2 * w + (j >> 1), kh = j & 1;
        aS[j] = A + (size_t)(bm + 16 * rf + lr) * 768 + 32 * kh + 8 * lc;
        ldA[j] = rf * 1024 + kh * 512 + l * 8;
    }
    const u16* bS[3]; int ldB[3];
    #pragma unroll
    for (int j = 0; j < 3; ++j) {
        int c = 3 * w + j, rf = c >> 1, kh = c & 1;
        bS[j] = Bt + (size_t)(bn + 16 * rf + lr) * 768 + 32 * kh + 8 * lc;
        ldB[j] = 16384 + rf * 1024 + kh * 512 + l * 8;
    }

    f32x4 acc[8][3] = {};
    bf16x8 afr[4][2], b0[2][2], b1[2];

    // prologue: B(0)x3, A(0)x4 -> buf0; B(1)x3 -> buf1; wait leaves B(1)
    #pragma unroll
    for (int j = 0; j < 3; ++j) gl2lds16(bS[j], &S[0][ldB[j]]);
    #pragma unroll
    for (int j = 0; j < 4; ++j) gl2lds16(aS[j], &S[0][ldA[j]]);
    #pragma unroll
    for (int j = 0; j < 3; ++j) gl2lds16(bS[j] + 64, &S[1][ldB[j]]);
    WAIT_VM(3); RAW_BARRIER();

    #pragma unroll 1
    for (int tt = 0; tt < NT; ++tt) {
        const int bf = tt & 1, ob = bf ^ 1;
        const u16* Sa = &S[bf][0];
        const u16* Sb = &S[bf][16384];
        #define LDS_A(ii, hh) (*(const bf16x8*)&Sa[((wm * 8 + (ii)) * 128 + (hh) * 64 + l) * 8])
        #define LDS_B(jj, hh) (*(const bf16x8*)&Sb[((3 * wn + (jj)) * 128 + (hh) * 64 + l) * 8])
        #define MM(ii, jj, BF0, BF1) { \
            acc[ii][jj] = MFMA(afr[(ii) & 3][0], BF0, acc[ii][jj], 0, 0, 0); \
            acc[ii][jj] = MFMA(afr[(ii) & 3][1], BF1, acc[ii][jj], 0, 0, 0); }
        // Phase A: read A rows 0-3 + ALL B coltiles; stage A(t+1) x4
        #pragma unroll
        for (int i = 0; i < 4; ++i) { afr[i][0] = LDS_A(i, 0); afr[i][1] = LDS_A(i, 1); }
        #pragma unroll
        for (int j = 0; j < 2; ++j) { b0[j][0] = LDS_B(j, 0); b0[j][1] = LDS_B(j, 1); }
        b1[0] = LDS_B(2, 0); b1[1] = LDS_B(2, 1);
        if (tt + 1 < NT) { gl2lds16(aS[0] + 64 * (tt + 1), &S[ob][ldA[0]]);
                           gl2lds16(aS[1] + 64 * (tt + 1), &S[ob][ldA[1]]);
                           gl2lds16(aS[2] + 64 * (tt + 1), &S[ob][ldA[2]]);
                           gl2lds16(aS[3] + 64 * (tt + 1), &S[ob][ldA[3]]); }
        RAW_BARRIER();
        __builtin_amdgcn_s_setprio(1);
        #pragma unroll
        for (int i = 0; i < 4; ++i) {
            MM(i, 0, b0[0][0], b0[0][1]);
            MM(i, 1, b0[1][0], b0[1][1]);
            MM(i, 2, b1[0],    b1[1]);
        }
        __builtin_amdgcn_s_setprio(0);
        SCHED_FENCE(); RAW_BARRIER();
        // Phase B: read A rows 4-7; stage B(t+2) into freed B-region
        #pragma unroll
        for (int i = 0; i < 4; ++i) { afr[i][0] = LDS_A(4 + i, 0); afr[i][1] = LDS_A(4 + i, 1); }
        if (tt + 2 < NT) { gl2lds16(bS[0] + 64 * (tt + 2), &S[bf][ldB[0]]);
                           gl2lds16(bS[1] + 64 * (tt + 2), &S[bf][ldB[1]]);
                           gl2lds16(bS[2] + 64 * (tt + 2), &S[bf][ldB[2]]); }
        RAW_BARRIER();
        __builtin_amdgcn_s_setprio(1);
        #pragma unroll
        for (int i = 0; i < 4; ++i) {
            MM(4 + i, 0, b0[0][0], b0[0][1]);
            MM(4 + i, 1, b0[1][0], b0[1][1]);
            MM(4 + i, 2, b1[0],    b1[1]);
        }
        __builtin_amdgcn_s_setprio(0);
        SCHED_FENCE();
        if (tt < NT - 2)       { WAIT_VM(3); }
        else if (tt == NT - 2) { WAIT_VM(0); }
        RAW_BARRIER();
        #undef LDS_A
        #undef LDS_B
        #undef MM
    }

    // ---- epilogue: LDS transpose (S free after final barrier) ----
    u16* Ct = &S[0][0];                       // [256][COLP] u16 = 99.3 KB
    if (bn < 1536) {
        int bidx = bm >> 10;
        #pragma unroll
        for (int i = 0; i < 8; ++i) {
            int lrow = wm * 128 + 16 * i + 4 * g;
            int tok = bm + lrow;
            #pragma unroll
            for (int j = 0; j < 3; ++j) {
                int lcol = wn * 48 + 16 * j + cid;
                int col = bn + lcol;
                int sel = col >= 768 ? 1 : 0;
                int cc = col - 768 * sel;
                int hh = cc >> 6, yy = cc & 63;
                u16x4 tv;
                #pragma unroll
                for (int r = 0; r < 4; ++r) {
                    u16 bv = f2bf(acc[i][j][r]);
                    tv[r] = bv;
                    Ct[(lrow + r) * COLP + lcol] = bv;
                }
                *(u16x4*)&qkT[((((size_t)bidx * 12 + hh) * 2 + sel) * 64 + yy) * 1024 + (tok & 1023)] = tv;
            }
        }
        RAW_BARRIER();
        #pragma unroll
        for (int it = 0; it < 12; ++it) {
            int f = t + 512 * it;             // 6144 chunks = 256 rows x 24
            int row = f / 24, cch = f - row * 24;
            u16x8 v = *(const u16x8*)&Ct[row * COLP + cch * 8];
            *(u16x8*)&qkb[(size_t)(bm + row) * 1536 + bn + cch * 8] = v;
        }
    } else {
        #pragma unroll
        for (int i = 0; i < 8; ++i) {
            int lrow = wm * 128 + 16 * i + 4 * g;
            #pragma unroll
            for (int j = 0; j < 3; ++j) {
                int lcol = wn * 48 + 16 * j + cid;
                #pragma unroll
                for (int r = 0; r < 4; ++r)
                    Ct[(lrow + r) * COLP + lcol] = f2bf(fmaxf(acc[i][j][r], 0.0f));
            }
        }
        RAW_BARRIER();
        #pragma unroll
        for (int it = 0; it < 12; ++it) {
            int f = t + 512 * it;
            int row = f / 24, cch = f - row * 24;
            u16x8 v = *(const u16x8*)&Ct[row * COLP + cch * 8];
            *(u16x8*)&midb[(size_t)(bm + row) * 4608 + bn + cch * 8] = v;
        }
    }
}

// ------- update GEMM: part[z] = mid . WcatT (K-half z), bf16 partials -------
// Grid 256 = 8 XCD x (2 z x 4 n x 4 m) = EXACTLY 1.0 round. K=2304.
__global__ __launch_bounds__(512) void gemm_upd(
    const u16* __restrict__ A,      // mid [8192 x 4608]
    const u16* __restrict__ Bt,     // WcatT [768 x 4608]
    u16* __restrict__ part)         // [2][8192][768] bf16
{
    __shared__ __align__(16) u16 S[2][28672];
    const int t = threadIdx.x, w = t >> 6, l = t & 63, g = l >> 4, cid = l & 15;
    const int lr = l & 15, lc = l >> 4;
    const int wm = w >> 2, wn = w & 3;
    const int flat = blockIdx.x;
    const int xcd = flat & 7, slot = flat >> 3;   // 32 slots per XCD
    const int z = slot >> 4, rem = slot & 15;     // z-outer (B z-slice L2-hot)
    const int nid = rem >> 2, mloc = rem & 3;
    const int bm = (xcd * 4 + mloc) * 256, bn = nid * 192;
    const int kbeg = z * 2304;
    const int NT = 36;                            // 2304 = 36 x 64
    u16* out = part + (size_t)z * 8192 * 768;

    const u16* aS[4]; int ldA[4];
    #pragma unroll
    for (int j = 0; j < 4; ++j) {
        int rf = 2 * w + (j >> 1), kh = j & 1;
        aS[j] = A + (size_t)(bm + 16 * rf + lr) * 4608 + kbeg + 32 * kh + 8 * lc;
        ldA[j] = rf * 1024 + kh * 512 + l * 8;
    }
    const u16* bS[3]; int ldB[3];
    #pragma unroll
    for (int j = 0; j < 3; ++j) {
        int c = 3 * w + j, rf = c >> 1, kh = c & 1;
        bS[j] = Bt + (size_t)(bn + 16 * rf + lr) * 4608 + kbeg + 32 * kh + 8 * lc;
        ldB[j] = 16384 + rf * 1024 + kh * 512 + l * 8;
    }

    f32x4 acc[8][3] = {};
    bf16x8 afr[4][2], b0[2][2], b1[2];

    #pragma unroll
    for (int j = 0; j < 3; ++j) gl2lds16(bS[j], &S[0][ldB[j]]);
    #pragma unroll
    for (int j = 0; j < 4; ++j) gl2lds16(aS[j], &S[0][ldA[j]]);
    #pragma unroll
    for (int j = 0; j < 3; ++j) gl2lds16(bS[j] + 64, &S[1][ldB[j]]);
    WAIT_VM(3); RAW_BARRIER();

    #pragma unroll 1
    for (int tt = 0; tt < NT; ++tt) {
        const int bf = tt & 1, ob = bf ^ 1;
        const u16* Sa = &S[bf][0];
        const u16* Sb = &S[bf][16384];
        #define LDS_A(ii, hh) (*(const bf16x8*)&Sa[((wm * 8 + (ii)) * 128 + (hh) * 64 + l) * 8])
        #define LDS_B(jj, hh) (*(const bf16x8*)&Sb[((3 * wn + (jj)) * 128 + (hh) * 64 + l) * 8])
        #define MM(ii, jj, BF0, BF1) { \
            acc[ii][jj] = MFMA(afr[(ii) & 3][0], BF0, acc[ii][jj], 0, 0, 0); \
            acc[ii][jj] = MFMA(afr[(ii) & 3][1], BF1, acc[ii][jj], 0, 0, 0); }
        #pragma unroll
        for (int i = 0; i < 4; ++i) { afr[i][0] = LDS_A(i, 0); afr[i][1] = LDS_A(i, 1); }
        #pragma unroll
        for (int j = 0; j < 2; ++j) { b0[j][0] = LDS_B(j, 0); b0[j][1] = LDS_B(j, 1); }
        b1[0] = LDS_B(2, 0); b1[1] = LDS_B(2, 1);
        if (tt + 1 < NT) { gl2lds16(aS[0] + 64 * (tt + 1), &S[ob][ldA[0]]);
                           gl2lds16(aS[1] + 64 * (tt + 1), &S[ob][ldA[1]]);
                           gl2lds16(aS[2] + 64 * (tt + 1), &S[ob][ldA[2]]);
                           gl2lds16(aS[3] + 64 * (tt + 1), &S[ob][ldA[3]]); }
        RAW_BARRIER();
        __builtin_amdgcn_s_setprio(1);
        #pragma unroll
        for (int i = 0; i < 4; ++i) {
            MM(i, 0, b0[0][0], b0[0][1]);
            MM(i, 1, b0[1][0], b0[1][1]);
            MM(i, 2, b1[0],    b1[1]);
        }
        __builtin_amdgcn_s_setprio(0);
        SCHED_FENCE(); RAW_BARRIER();
        #pragma unroll
        for (int i = 0; i < 4; ++i) { afr[i][0] = LDS_A(4 + i, 0); afr[i][1] = LDS_A(4 + i, 1); }
        if (tt + 2 < NT) { gl2lds16(bS[0] + 64 * (tt + 2), &S[bf][ldB[0]]);
                           gl2lds16(bS[1] + 64 * (tt + 2), &S[bf][ldB[1]]);
                           gl2lds16(bS[2] + 64 * (tt + 2), &S[bf][ldB[2]]); }
        RAW_BARRIER();
        __builtin_amdgcn_s_setprio(1);
        #pragma unroll
        for (int i = 0; i < 4; ++i) {
            MM(4 + i, 0, b0[0][0], b0[0][1]);
            MM(4 + i, 1, b0[1][0], b0[1][1]);
            MM(4 + i, 2, b1[0],    b1[1]);
        }
        __builtin_amdgcn_s_setprio(0);
        SCHED_FENCE();
        if (tt < NT - 2)       { WAIT_VM(3); }
        else if (tt == NT - 2) { WAIT_VM(0); }
        RAW_BARRIER();
        #undef LDS_A
        #undef LDS_B
        #undef MM
    }

    // ---- epilogue: LDS transpose + coalesced u16x8 stores ----
    u16* Ct = &S[0][0];
    #pragma unroll
    for (int i = 0; i < 8; ++i) {
        int lrow = wm * 128 + 16 * i + 4 * g;
        #pragma unroll
        for (int j = 0; j < 3; ++j) {
            int lcol = wn * 48 + 16 * j + cid;
            #pragma unroll
            for (int r = 0; r < 4; ++r)
                Ct[(lrow + r) * COLP + lcol] = f2bf(acc[i][j][r]);
        }
    }
    RAW_BARRIER();
    #pragma unroll
    for (int it = 0; it < 12; ++it) {
        int f = t + 512 * it;
        int row = f / 24, cch = f - row * 24;
        u16x8 v = *(const u16x8*)&Ct[row * COLP + cch * 8];
        *(u16x8*)&out[(size_t)(bm + row) * 768 + bn + cch * 8] = v;
    }
}

// ---------------- dq: flash pass over k, 128-q tile, computes L and Aq -------
__global__ __launch_bounds__(256) void dq_kernel(const u16* __restrict__ qk,
    const u16* __restrict__ qkT, float* __restrict__ L, u16* __restrict__ mid)
{
    const int flat = blockIdx.x;
    const int xcd = flat & 7, slot = flat >> 3;       // 96 slots per XCD
    const int bh = xcd * 12 + slot / 8;               // 12 bh per XCD
    const int q0 = (slot % 8) << 7;
    const int b = bh / H_, h = bh % H_;
    const u16* qbase = qk + (size_t)b * 1024 * 1536 + h * 64;
    const u16* kbase = qbase + 768;
    const u16* ktg = qkT + ((size_t)bh * 2 + 1) * 64 * 1024;   // K^T [y][1024]
    __shared__ __align__(16) u16 KB[2][8192];   // per buf: Kn [0,4096) | Kt [4096,8192)
    __shared__ __align__(16) u16 Ps[8192];
    const int t = threadIdx.x, w = t >> 6, l = t & 63, g = l >> 4, cid = l & 15;
    const int lr = l & 15, lc = l >> 4;

    #pragma unroll
    for (int h2 = 0; h2 < 2; ++h2)
        #pragma unroll
        for (int ch = 0; ch < 2; ++ch)
            gl2lds16(&qbase[(size_t)(q0 + 32 * w + 16 * h2 + lr) * 1536 + 32 * ch + 8 * lc],
                     &KB[0][(128 * (2 * w + h2) + 64 * ch + l) * 8]);
    __syncthreads();
    bf16x8 QF[2][2];
    #pragma unroll
    for (int jj = 0; jj < 2; ++jj)
        #pragma unroll
        for (int hh = 0; hh < 2; ++hh)
            QF[jj][hh] = *(const bf16x8*)&KB[0][(128 * (2 * w + jj) + 64 * hh + l) * 8];
    __syncthreads();   // all QF reads done before KB[0] is restaged

    auto stageK = [&](int buf, int kt) {   // 4 gl2lds per wave
        #pragma unroll
        for (int ch = 0; ch < 2; ++ch) {
            gl2lds16(&kbase[(size_t)(kt * 64 + 16 * w + lr) * 1536 + 32 * ch + 8 * lc],
                     &KB[buf][(128 * w + 64 * ch + l) * 8]);
            gl2lds16(&ktg[(size_t)(16 * w + lr) * 1024 + kt * 64 + 32 * ch + 8 * lc],
                     &KB[buf][4096 + (128 * w + 64 * ch + l) * 8]);
        }
    };

    f32x4 acc[2][4] = {};
    float lrun[2] = {0.0f, 0.0f};

    stageK(0, 0); stageK(1, 1);
    #pragma unroll 1
    for (int kt = 0; kt < 16; ++kt) {
        if (kt == 15) { WAIT_VM(0); } else { WAIT_VM(4); }
        RAW_BARRIER();
        const int buf = kt & 1;
        const u16* Kn = &KB[buf][0];
        const u16* Kt = &KB[buf][4096];
        f32x4 s[4][2];
        #pragma unroll
        for (int i = 0; i < 4; ++i) {
            bf16x8 a0 = *(const bf16x8*)&Kn[(128 * i + l) * 8];
            bf16x8 a1 = *(const bf16x8*)&Kn[(128 * i + 64 + l) * 8];
            #pragma unroll
            for (int jj = 0; jj < 2; ++jj) {
                f32x4 z = {0.f, 0.f, 0.f, 0.f};
                z = MFMA(a0, QF[jj][0], z, 0, 0, 0);
                z = MFMA(a1, QF[jj][1], z, 0, 0, 0);
                s[i][jj] = z;
            }
        }
        #pragma unroll
        for (int jj = 0; jj < 2; ++jj) {
            float psum = 0.0f;
            #pragma unroll
            for (int i = 0; i < 4; ++i) {
                u16x4 pv;
                #pragma unroll
                for (int r = 0; r < 4; ++r) {
                    float p = EXP2F(s[i][jj][r] * B2L_);
                    psum += p;
                    pv[r] = f2bf_rz(p);
                }
                *(u16x4*)&Ps[(128 * (2 * w + jj) + 32 * i + 16 * (g >> 1) + cid) * 8 + 4 * (g & 1)] = pv;
            }
            psum += __shfl_xor(psum, 16);
            psum += __shfl_xor(psum, 32);
            lrun[jj] += psum;
        }
        #pragma unroll
        for (int jj = 0; jj < 2; ++jj) {
            bf16x8 p0 = *(const bf16x8*)&Ps[(128 * (2 * w + jj) + l) * 8];
            bf16x8 p1 = *(const bf16x8*)&Ps[(128 * (2 * w + jj) + 64 + l) * 8];
            #pragma unroll
            for (int j = 0; j < 4; ++j) {
                acc[jj][j] = MFMA(p0, *(const bf16x8*)&Kt[(128 * j + l) * 8], acc[jj][j], 0, 0, 0);
                acc[jj][j] = MFMA(p1, *(const bf16x8*)&Kt[(128 * j + 64 + l) * 8], acc[jj][j], 0, 0, 0);
            }
        }
        RAW_BARRIER();
        if (kt + 2 < 16) stageK(buf, kt + 2);
    }
    #pragma unroll
    for (int jj = 0; jj < 2; ++jj) {
        if (g == 0)
            L[(size_t)bh * 1024 + q0 + 32 * w + 16 * jj + cid] = __logf(lrun[jj]);
        float linv = 1.0f / lrun[jj];
        #pragma unroll
        for (int r = 0; r < 4; ++r) {
            float fr = __shfl(linv, 4 * g + r);
            int row = q0 + 32 * w + 16 * jj + 4 * g + r;
            #pragma unroll
            for (int j = 0; j < 4; ++j)
                mid[(size_t)(b * 1024 + row) * 4608 + h * 64 + 16 * j + cid] = f2bf(acc[jj][j][r] * fr);
        }
    }
}

// ---------------- dk: Ak[k] = sum_q exp(beta*S - L[q]) q, 128-k tile --------
__global__ __launch_bounds__(256) void dk_kernel(const u16* __restrict__ qk,
    const u16* __restrict__ qkT, const float* __restrict__ L, u16* __restrict__ mid)
{
    const int flat = blockIdx.x;
    const int xcd = flat & 7, slot = flat >> 3;
    const int bh = xcd * 12 + slot / 8;
    const int k0 = (slot % 8) << 7;
    const int b = bh / H_, h = bh % H_;
    const u16* qbase = qk + (size_t)b * 1024 * 1536 + h * 64;
    const u16* kbase = qbase + 768;
    const u16* qtg = qkT + ((size_t)bh * 2 + 0) * 64 * 1024;   // Q^T [y][1024]
    __shared__ __align__(16) u16 KB[2][8192];   // per buf: Qn [0,4096) | Qt [4096,8192)
    __shared__ __align__(16) u16 Ps[8192];
    const int t = threadIdx.x, w = t >> 6, l = t & 63, g = l >> 4, cid = l & 15;
    const int lr = l & 15, lc = l >> 4;

    #pragma unroll
    for (int h2 = 0; h2 < 2; ++h2)
        #pragma unroll
        for (int ch = 0; ch < 2; ++ch)
            gl2lds16(&kbase[(size_t)(k0 + 32 * w + 16 * h2 + lr) * 1536 + 32 * ch + 8 * lc],
                     &KB[0][(128 * (2 * w + h2) + 64 * ch + l) * 8]);
    __syncthreads();
    bf16x8 KF[2][2];
    #pragma unroll
    for (int jj = 0; jj < 2; ++jj)
        #pragma unroll
        for (int hh = 0; hh < 2; ++hh)
            KF[jj][hh] = *(const bf16x8*)&KB[0][(128 * (2 * w + jj) + 64 * hh + l) * 8];
    __syncthreads();

    auto stageQ = [&](int buf, int qt) {   // 4 gl2lds per wave
        #pragma unroll
        for (int ch = 0; ch < 2; ++ch) {
            gl2lds16(&qbase[(size_t)(qt * 64 + 16 * w + lr) * 1536 + 32 * ch + 8 * lc],
                     &KB[buf][(128 * w + 64 * ch + l) * 8]);
            gl2lds16(&qtg[(size_t)(16 * w + lr) * 1024 + qt * 64 + 32 * ch + 8 * lc],
                     &KB[buf][4096 + (128 * w + 64 * ch + l) * 8]);
        }
    };

    f32x4 acc[2][4] = {};
    stageQ(0, 0); stageQ(1, 1);
    #pragma unroll 1
    for (int qt = 0; qt < 16; ++qt) {
        if (qt == 15) { WAIT_VM(0); } else { WAIT_VM(4); }
        RAW_BARRIER();
        const int buf = qt & 1;
        const u16* Qn = &KB[buf][0];
        const u16* Qt = &KB[buf][4096];
        #pragma unroll
        for (int i = 0; i < 4; ++i) {
            bf16x8 a0 = *(const bf16x8*)&Qn[(128 * i + l) * 8];
            bf16x8 a1 = *(const bf16x8*)&Qn[(128 * i + 64 + l) * 8];
            f32x4 lv = *(const f32x4*)&L[(size_t)bh * 1024 + qt * 64 + 16 * i + 4 * g];
            f32x4 lv2;
            #pragma unroll
            for (int r = 0; r < 4; ++r) lv2[r] = lv[r] * L2E_;
            #pragma unroll
            for (int jj = 0; jj < 2; ++jj) {
                f32x4 z = {0.f, 0.f, 0.f, 0.f};
                z = MFMA(a0, KF[jj][0], z, 0, 0, 0);
                z = MFMA(a1, KF[jj][1], z, 0, 0, 0);
                u16x4 pv;
                #pragma unroll
                for (int r = 0; r < 4; ++r)
                    pv[r] = f2bf_rz(EXP2F(fmaf(z[r], B2L_, -lv2[r])));
                *(u16x4*)&Ps[(128 * (2 * w + jj) + 32 * i + 16 * (g >> 1) + cid) * 8 + 4 * (g & 1)] = pv;
            }
        }
        #pragma unroll
        for (int jj = 0; jj < 2; ++jj) {
            bf16x8 p0 = *(const bf16x8*)&Ps[(128 * (2 * w + jj) + l) * 8];
            bf16x8 p1 = *(const bf16x8*)&Ps[(128 * (2 * w + jj) + 64 + l) * 8];
            #pragma unroll
            for (int j = 0; j < 4; ++j) {
                acc[jj][j] = MFMA(p0, *(const bf16x8*)&Qt[(128 * j + l) * 8], acc[jj][j], 0, 0, 0);
                acc[jj][j] = MFMA(p1, *(const bf16x8*)&Qt[(128 * j + 64 + l) * 8], acc[jj][j], 0, 0, 0);
            }
        }
        RAW_BARRIER();
        if (qt + 2 < 16) stageQ(buf, qt + 2);
    }
    #pragma unroll
    for (int jj = 0; jj < 2; ++jj)
        #pragma unroll
        for (int r = 0; r < 4; ++r) {
            int row = k0 + 32 * w + 16 * jj + 4 * g + r;
            #pragma unroll
            for (int j = 0; j < 4; ++j)
                mid[(size_t)(b * 1024 + row) * 4608 + 768 + h * 64 + 16 * j + cid] = f2bf(acc[jj][j][r]);
        }
}

// ---------------------------------------------------------------------------
extern "C" void kernel_launch(void* const* d_in, const int* in_sizes, int n_in,
                              void* d_out, int out_size, void* d_ws, size_t ws_size,
                              hipStream_t stream)
{
    const float* x     = (const float*)d_in[0];
    const float* gamma = (const float*)d_in[1];
    const float* betap = (const float*)d_in[2];
    const float* Wq    = (const float*)d_in[3];
    const float* Wk    = (const float*)d_in[4];
    const float* xi    = (const float*)d_in[5];
    float* xc = (float*)d_out;

    char* p = (char*)d_ws;
    u16* wcat_bf  = (u16*)p; p += (size_t)4608 * 768 * 2;   // [Wq;Wk;xi] rows
    u16* wcatT_bf = (u16*)p; p += (size_t)768 * 4608 * 2;
    u16* g_bf     = (u16*)p; p += (size_t)NTOK * 768 * 2;
    u16* qk_bf    = (u16*)p; p += (size_t)NTOK * 1536 * 2;
    u16* qkT_bf   = (u16*)p; p += (size_t)96 * 2 * 64 * 1024 * 2;
    u16* mid_bf   = (u16*)p; p += (size_t)NTOK * 4608 * 2;
    float* L      = (float*)p; p += (size_t)96 * 1024 * 4;
    // part[2][8192][768] bf16 = 25.17 MB ALIASES qk_bf (25.17 MB exactly):
    // qk is dead once dq/dk complete; part is consumed by reduce_ln before
    // the next step's gemm_fwd rewrites qk.
    u16* part = qk_bf;
    (void)ws_size; (void)in_sizes; (void)n_in; (void)out_size;

    hipMemcpyAsync(xc, x, (size_t)NTOK * 768 * 4, hipMemcpyDeviceToDevice, stream);

    convert_bf<<<576, 256, 0, stream>>>(Wq, wcat_bf, 147456);
    convert_bf<<<576, 256, 0, stream>>>(Wk, wcat_bf + 768 * 768, 147456);
    convert_bf<<<2304, 256, 0, stream>>>(xi, wcat_bf + 2 * 768 * 768, 589824);
    transpose_bf<<<dim3(72, 12), 256, 0, stream>>>(Wq, Wk, xi, wcatT_bf);

    // g_0 = LN(x)
    ln_kernel<<<NTOK, 256, 0, stream>>>(x, gamma, betap, g_bf);

    for (int step = 0; step < STEPS_; ++step) {
        // fused: qk (+qkT) and relu-mid in one N=4608 GEMM (256x192, 2-phase)
        gemm_fwd<<<768, 512, 0, stream>>>(
            g_bf, wcat_bf, qk_bf, qkT_bf, mid_bf);
        // Aq (+L), Ak  (XCD-swizzled, ping-pong staged)
        dq_kernel<<<768, 256, 0, stream>>>(qk_bf, qkT_bf, L, mid_bf);
        dk_kernel<<<768, 256, 0, stream>>>(qk_bf, qkT_bf, L, mid_bf);
        // part[z] = mid . Wcat (2 K-halves, 256x192, 2-phase, 1.0 round)
        gemm_upd<<<256, 512, 0, stream>>>(mid_bf, wcatT_bf, part);
        // xc += alpha*(P0+P1); g = LN(xc)   (fused)
        reduce_ln<<<NTOK, 192, 0, stream>>>(part, xc, gamma, betap, g_bf);
    }
}

// Round 12
// 3007.114 us; speedup vs baseline: 1.2556x; 1.0056x over previous
//
#include <hip/hip_runtime.h>
#include <math.h>

#define H_ 12
#define STEPS_ 12
#define ALPHA_ 0.1f
#define EPS_ 1e-5f
#define BETA_ 0.125f          // 1/sqrt(64)
#define B2L_ 0.1803368801111204f   // BETA_ * log2(e)
#define L2E_ 1.4426950408889634f
#define NTOK 8192
#define COLP 196              // padded LDS cols: row stride 98 dwords ->
                              // 4-row groups at banks {0,8,16,24}, conflict-free

typedef unsigned short u16;
typedef __attribute__((ext_vector_type(8))) u16 u16x8;
typedef __attribute__((ext_vector_type(4))) u16 u16x4;
typedef __attribute__((ext_vector_type(4))) float f32x4;
typedef __attribute__((ext_vector_type(8))) __bf16 bf16x8;

#define MFMA __builtin_amdgcn_mfma_f32_16x16x32_bf16
#define EXP2F(x) __builtin_amdgcn_exp2f(x)

__device__ __forceinline__ u16 f2bf(float x) {
    unsigned u = __float_as_uint(x);
    u += 0x7FFFu + ((u >> 16) & 1u);
    return (u16)(u >> 16);
}
__device__ __forceinline__ float bf2f(u16 u) {
    return __uint_as_float(((unsigned)u) << 16);
}
// truncation pack (1 VALU) for positive P values — ≤0.4% rel err, RTZ
__device__ __forceinline__ u16 f2bf_rz(float x) {
    return (u16)(__float_as_uint(x) >> 16);
}

// async global->LDS, 16B per lane; LDS dst is wave-uniform base + 16*lane
__device__ __forceinline__ void gl2lds16(const u16* gsrc, u16* ldst) {
    __builtin_amdgcn_global_load_lds(
        (const __attribute__((address_space(1))) void*)gsrc,
        (__attribute__((address_space(3))) void*)ldst, 16, 0, 0);
}

// raw barrier / waitcnt (no compiler-attached vmcnt(0) drain)
#define RAW_BARRIER()   asm volatile("s_barrier" ::: "memory")
#define WAIT_VM(n)      asm volatile("s_waitcnt vmcnt(" #n ")" ::: "memory")
#define SCHED_FENCE()   __builtin_amdgcn_sched_barrier(0)

// ---------------- initial LayerNorm x -> bf16 g (once, pre-loop) -----------
__global__ __launch_bounds__(256) void ln_kernel(const float* __restrict__ x,
    const float* __restrict__ gamma, const float* __restrict__ beta,
    u16* __restrict__ g)
{
    int row = blockIdx.x;
    const float* xr = x + (size_t)row * 768;
    u16* gr = g + (size_t)row * 768;
    int t = threadIdx.x;
    float v0 = xr[t], v1 = xr[t + 256], v2 = xr[t + 512];
    float s = v0 + v1 + v2;
    #pragma unroll
    for (int off = 32; off > 0; off >>= 1) s += __shfl_down(s, off);
    __shared__ float red[8];
    int wid = t >> 6, lane = t & 63;
    if (lane == 0) red[wid] = s;
    __syncthreads();
    if (t == 0) red[0] = (red[0] + red[1] + red[2] + red[3]) * (1.0f / 768.0f);
    __syncthreads();
    float mu = red[0];
    float d0 = v0 - mu, d1 = v1 - mu, d2 = v2 - mu;
    float ss = d0*d0 + d1*d1 + d2*d2;
    #pragma unroll
    for (int off = 32; off > 0; off >>= 1) ss += __shfl_down(ss, off);
    if (lane == 0) red[4 + wid] = ss;
    __syncthreads();
    if (t == 0) red[4] = rsqrtf((red[4] + red[5] + red[6] + red[7]) * (1.0f / 768.0f) + EPS_);
    __syncthreads();
    float rs = red[4];
    gr[t]       = f2bf(gamma[t]       * d0 * rs + beta[t]);
    gr[t + 256] = f2bf(gamma[t + 256] * d1 * rs + beta[t + 256]);
    gr[t + 512] = f2bf(gamma[t + 512] * d2 * rs + beta[t + 512]);
}

// ------- fused: xc += alpha*(P0+P1); g = LN(xc)  (one block per row) --------
__global__ __launch_bounds__(192) void reduce_ln(const u16* __restrict__ part,
    float* __restrict__ xc, const float* __restrict__ gamma,
    const float* __restrict__ beta, u16* __restrict__ g)
{
    int row = blockIdx.x, t = threadIdx.x;
    const u16x4* p0 = (const u16x4*)(part + (size_t)row * 768);
    const u16x4* p1 = (const u16x4*)(part + (size_t)(8192 + row) * 768);
    f32x4* xr = (f32x4*)(xc + (size_t)row * 768);
    f32x4 v = xr[t];
    u16x4 a = p0[t], b = p1[t];
    #pragma unroll
    for (int e = 0; e < 4; ++e) v[e] = fmaf(ALPHA_, bf2f(a[e]) + bf2f(b[e]), v[e]);
    xr[t] = v;
    float s = (v[0] + v[1]) + (v[2] + v[3]);
    #pragma unroll
    for (int off = 32; off > 0; off >>= 1) s += __shfl_down(s, off);
    __shared__ float red[8];
    int wid = t >> 6, lane = t & 63;
    if (lane == 0) red[wid] = s;
    __syncthreads();
    if (t == 0) red[0] = (red[0] + red[1] + red[2]) * (1.0f / 768.0f);
    __syncthreads();
    float mu = red[0];
    f32x4 d;
    #pragma unroll
    for (int e = 0; e < 4; ++e) d[e] = v[e] - mu;
    float ss = (d[0]*d[0] + d[1]*d[1]) + (d[2]*d[2] + d[3]*d[3]);
    #pragma unroll
    for (int off = 32; off > 0; off >>= 1) ss += __shfl_down(ss, off);
    if (lane == 0) red[4 + wid] = ss;
    __syncthreads();
    if (t == 0) red[4] = rsqrtf((red[4] + red[5] + red[6]) * (1.0f / 768.0f) + EPS_);
    __syncthreads();
    float rs = red[4];
    const f32x4 gm = *(const f32x4*)&gamma[t * 4];
    const f32x4 bt = *(const f32x4*)&beta[t * 4];
    u16x4 o;
    #pragma unroll
    for (int e = 0; e < 4; ++e) o[e] = f2bf(fmaf(gm[e], d[e] * rs, bt[e]));
    *(u16x4*)&g[(size_t)row * 768 + t * 4] = o;
}

// ---------------- fp32 -> bf16 convert ----------------
__global__ __launch_bounds__(256) void convert_bf(const float* __restrict__ src,
                                                  u16* __restrict__ dst, int n4)
{
    int i = blockIdx.x * 256 + threadIdx.x;
    if (i < n4) {
        f32x4 v = *(const f32x4*)&src[i * 4];
        u16x4 o;
        #pragma unroll
        for (int e = 0; e < 4; ++e) o[e] = f2bf(v[e]);
        *(u16x4*)&dst[i * 4] = o;
    }
}

// -------- transpose-convert: Wcat [4608x768] f32 -> WcatT [768x4608] bf16 ----
__global__ __launch_bounds__(256) void transpose_bf(const float* __restrict__ Wq,
    const float* __restrict__ Wk, const float* __restrict__ xi, u16* __restrict__ out)
{
    __shared__ float tile[64][65];
    int rb = blockIdx.x * 64, cb = blockIdx.y * 64;
    const float* src;
    if (rb < 768) src = Wq + (size_t)rb * 768;
    else if (rb < 1536) src = Wk + (size_t)(rb - 768) * 768;
    else src = xi + (size_t)(rb - 1536) * 768;
    int t = threadIdx.x;
    #pragma unroll
    for (int it = 0; it < 4; ++it) {
        int r = (t >> 4) + 16 * it;
        f32x4 v = *(const f32x4*)&src[(size_t)r * 768 + cb + (t & 15) * 4];
        #pragma unroll
        for (int e = 0; e < 4; ++e) tile[r][(t & 15) * 4 + e] = v[e];
    }
    __syncthreads();
    #pragma unroll
    for (int it = 0; it < 4; ++it) {
        int cl = (t >> 4) + 16 * it;
        u16x4 o;
        #pragma unroll
        for (int e = 0; e < 4; ++e) o[e] = f2bf(tile[(t & 15) * 4 + e][cl]);
        *(u16x4*)&out[(size_t)(cb + cl) * 4608 + rb + (t & 15) * 4] = o;
    }
}

// ======== 256x192 TWO-phase GEMM core (R8) ==================================
// fwd: R8 direct-store epilogue (fire-and-forget overlaps next block's
// prologue across its 3 rounds — LDS roundtrip there measured -12us/step).
// upd: LDS-transposed epilogue (COLP=196, conflict-free) — critical-path
// stores feed reduce_ln; coalescing measured +13us/step.

// ---------------- fused fwd GEMM: [qk | relu-mid] = g . Wcat^T --------------
// Grid 768 = 8 XCD x (24 n x 4 m).
__global__ __launch_bounds__(512) void gemm_fwd(
    const u16* __restrict__ A,      // g [8192 x 768]
    const u16* __restrict__ Bt,     // Wcat rows [4608 x 768] (Wq|Wk|xi)
    u16* __restrict__ qkb, u16* __restrict__ qkT, u16* __restrict__ midb)
{
    // per buffer (28672 u16 = 56 KB): A [0,16384) 256rx64k, B [16384,28672) 192rx64k
    __shared__ __align__(16) u16 S[2][28672];
    const int t = threadIdx.x, w = t >> 6, l = t & 63, g = l >> 4, cid = l & 15;
    const int lr = l & 15, lc = l >> 4;
    const int wm = w >> 2, wn = w & 3;
    const int flat = blockIdx.x;
    const int xcd = flat & 7, slot = flat >> 3;   // 96 slots per XCD
    const int nid = slot >> 2, mloc = slot & 3;
    const int bm = (xcd * 4 + mloc) * 256;        // 32 m-tiles
    const int bn = nid * 192;                     // 24 n-tiles
    const int NT = 12;                            // K = 768 = 12 x 64

    // staging: A chunks j=0..3 (rf=2w+(j>>1), kh=j&1); B chunks j=0..2 (c=3w+j)
    const u16* aS[4]; int ldA[4];
    #pragma unroll
    for (int j = 0; j < 4; ++j) {
        int rf = 2 * w + (j >> 1), kh = j & 1;
        aS[j] = A + (size_t)(bm + 16 * rf + lr) * 768 + 32 * kh + 8 * lc;
        ldA[j] = rf * 1024 + kh * 512 + l * 8;
    }
    const u16* bS[3]; int ldB[3];
    #pragma unroll
    for (int j = 0; j < 3; ++j) {
        int c = 3 * w + j, rf = c >> 1, kh = c & 1;
        bS[j] = Bt + (size_t)(bn + 16 * rf + lr) * 768 + 32 * kh + 8 * lc;
        ldB[j] = 16384 + rf * 1024 + kh * 512 + l * 8;
    }

    f32x4 acc[8][3] = {};
    bf16x8 afr[4][2], b0[2][2], b1[2];

    // prologue: B(0)x3, A(0)x4 -> buf0; B(1)x3 -> buf1; wait leaves B(1)
    #pragma unroll
    for (int j = 0; j < 3; ++j) gl2lds16(bS[j], &S[0][ldB[j]]);
    #pragma unroll
    for (int j = 0; j < 4; ++j) gl2lds16(aS[j], &S[0][ldA[j]]);
    #pragma unroll
    for (int j = 0; j < 3; ++j) gl2lds16(bS[j] + 64, &S[1][ldB[j]]);
    WAIT_VM(3); RAW_BARRIER();

    #pragma unroll 1
    for (int tt = 0; tt < NT; ++tt) {
        const int bf = tt & 1, ob = bf ^ 1;
        const u16* Sa = &S[bf][0];
        const u16* Sb = &S[bf][16384];
        #define LDS_A(ii, hh) (*(const bf16x8*)&Sa[((wm * 8 + (ii)) * 128 + (hh) * 64 + l) * 8])
        #define LDS_B(jj, hh) (*(const bf16x8*)&Sb[((3 * wn + (jj)) * 128 + (hh) * 64 + l) * 8])
        #define MM(ii, jj, BF0, BF1) { \
            acc[ii][jj] = MFMA(afr[(ii) & 3][0], BF0, acc[ii][jj], 0, 0, 0); \
            acc[ii][jj] = MFMA(afr[(ii) & 3][1], BF1, acc[ii][jj], 0, 0, 0); }
        // Phase A: read A rows 0-3 + ALL B coltiles; stage A(t+1) x4
        #pragma unroll
        for (int i = 0; i < 4; ++i) { afr[i][0] = LDS_A(i, 0); afr[i][1] = LDS_A(i, 1); }
        #pragma unroll
        for (int j = 0; j < 2; ++j) { b0[j][0] = LDS_B(j, 0); b0[j][1] = LDS_B(j, 1); }
        b1[0] = LDS_B(2, 0); b1[1] = LDS_B(2, 1);
        if (tt + 1 < NT) { gl2lds16(aS[0] + 64 * (tt + 1), &S[ob][ldA[0]]);
                           gl2lds16(aS[1] + 64 * (tt + 1), &S[ob][ldA[1]]);
                           gl2lds16(aS[2] + 64 * (tt + 1), &S[ob][ldA[2]]);
                           gl2lds16(aS[3] + 64 * (tt + 1), &S[ob][ldA[3]]); }
        RAW_BARRIER();
        __builtin_amdgcn_s_setprio(1);
        #pragma unroll
        for (int i = 0; i < 4; ++i) {
            MM(i, 0, b0[0][0], b0[0][1]);
            MM(i, 1, b0[1][0], b0[1][1]);
            MM(i, 2, b1[0],    b1[1]);
        }
        __builtin_amdgcn_s_setprio(0);
        SCHED_FENCE(); RAW_BARRIER();
        // Phase B: read A rows 4-7; stage B(t+2) into freed B-region
        #pragma unroll
        for (int i = 0; i < 4; ++i) { afr[i][0] = LDS_A(4 + i, 0); afr[i][1] = LDS_A(4 + i, 1); }
        if (tt + 2 < NT) { gl2lds16(bS[0] + 64 * (tt + 2), &S[bf][ldB[0]]);
                           gl2lds16(bS[1] + 64 * (tt + 2), &S[bf][ldB[1]]);
                           gl2lds16(bS[2] + 64 * (tt + 2), &S[bf][ldB[2]]); }
        RAW_BARRIER();
        __builtin_amdgcn_s_setprio(1);
        #pragma unroll
        for (int i = 0; i < 4; ++i) {
            MM(4 + i, 0, b0[0][0], b0[0][1]);
            MM(4 + i, 1, b0[1][0], b0[1][1]);
            MM(4 + i, 2, b1[0],    b1[1]);
        }
        __builtin_amdgcn_s_setprio(0);
        SCHED_FENCE();
        if (tt < NT - 2)       { WAIT_VM(3); }
        else if (tt == NT - 2) { WAIT_VM(0); }
        RAW_BARRIER();
        #undef LDS_A
        #undef LDS_B
        #undef MM
    }

    if (bn < 1536) {
        int bidx = bm >> 10;
        #pragma unroll
        for (int i = 0; i < 8; ++i) {
            int tok = bm + wm * 128 + 16 * i + 4 * g;
            #pragma unroll
            for (int j = 0; j < 3; ++j) {
                int col = bn + wn * 48 + 16 * j + cid;
                int sel = col >= 768 ? 1 : 0;
                int cc = col - 768 * sel;
                int hh = cc >> 6, yy = cc & 63;
                u16x4 tv;
                #pragma unroll
                for (int r = 0; r < 4; ++r) {
                    u16 bv = f2bf(acc[i][j][r]);
                    tv[r] = bv;
                    qkb[(size_t)(tok + r) * 1536 + col] = bv;
                }
                *(u16x4*)&qkT[((((size_t)bidx * 12 + hh) * 2 + sel) * 64 + yy) * 1024 + (tok & 1023)] = tv;
            }
        }
    } else {
        #pragma unroll
        for (int i = 0; i < 8; ++i)
            #pragma unroll
            for (int r = 0; r < 4; ++r) {
                size_t row = bm + wm * 128 + 16 * i + 4 * g + r;
                #pragma unroll
                for (int j = 0; j < 3; ++j) {
                    int col = bn + wn * 48 + 16 * j + cid;
                    midb[row * 4608 + col] = f2bf(fmaxf(acc[i][j][r], 0.0f));
                }
            }
    }
}

// ------- update GEMM: part[z] = mid . WcatT (K-half z), bf16 partials -------
// Grid 256 = 8 XCD x (2 z x 4 n x 4 m) = EXACTLY 1.0 round. K=2304.
__global__ __launch_bounds__(512) void gemm_upd(
    const u16* __restrict__ A,      // mid [8192 x 4608]
    const u16* __restrict__ Bt,     // WcatT [768 x 4608]
    u16* __restrict__ part)         // [2][8192][768] bf16
{
    __shared__ __align__(16) u16 S[2][28672];
    const int t = threadIdx.x, w = t >> 6, l = t & 63, g = l >> 4, cid = l & 15;
    const int lr = l & 15, lc = l >> 4;
    const int wm = w >> 2, wn = w & 3;
    const int flat = blockIdx.x;
    const int xcd = flat & 7, slot = flat >> 3;   // 32 slots per XCD
    const int z = slot >> 4, rem = slot & 15;     // z-outer (B z-slice L2-hot)
    const int nid = rem >> 2, mloc = rem & 3;
    const int bm = (xcd * 4 + mloc) * 256, bn = nid * 192;
    const int kbeg = z * 2304;
    const int NT = 36;                            // 2304 = 36 x 64
    u16* out = part + (size_t)z * 8192 * 768;

    const u16* aS[4]; int ldA[4];
    #pragma unroll
    for (int j = 0; j < 4; ++j) {
        int rf = 2 * w + (j >> 1), kh = j & 1;
        aS[j] = A + (size_t)(bm + 16 * rf + lr) * 4608 + kbeg + 32 * kh + 8 * lc;
        ldA[j] = rf * 1024 + kh * 512 + l * 8;
    }
    const u16* bS[3]; int ldB[3];
    #pragma unroll
    for (int j = 0; j < 3; ++j) {
        int c = 3 * w + j, rf = c >> 1, kh = c & 1;
        bS[j] = Bt + (size_t)(bn + 16 * rf + lr) * 4608 + kbeg + 32 * kh + 8 * lc;
        ldB[j] = 16384 + rf * 1024 + kh * 512 + l * 8;
    }

    f32x4 acc[8][3] = {};
    bf16x8 afr[4][2], b0[2][2], b1[2];

    #pragma unroll
    for (int j = 0; j < 3; ++j) gl2lds16(bS[j], &S[0][ldB[j]]);
    #pragma unroll
    for (int j = 0; j < 4; ++j) gl2lds16(aS[j], &S[0][ldA[j]]);
    #pragma unroll
    for (int j = 0; j < 3; ++j) gl2lds16(bS[j] + 64, &S[1][ldB[j]]);
    WAIT_VM(3); RAW_BARRIER();

    #pragma unroll 1
    for (int tt = 0; tt < NT; ++tt) {
        const int bf = tt & 1, ob = bf ^ 1;
        const u16* Sa = &S[bf][0];
        const u16* Sb = &S[bf][16384];
        #define LDS_A(ii, hh) (*(const bf16x8*)&Sa[((wm * 8 + (ii)) * 128 + (hh) * 64 + l) * 8])
        #define LDS_B(jj, hh) (*(const bf16x8*)&Sb[((3 * wn + (jj)) * 128 + (hh) * 64 + l) * 8])
        #define MM(ii, jj, BF0, BF1) { \
            acc[ii][jj] = MFMA(afr[(ii) & 3][0], BF0, acc[ii][jj], 0, 0, 0); \
            acc[ii][jj] = MFMA(afr[(ii) & 3][1], BF1, acc[ii][jj], 0, 0, 0); }
        #pragma unroll
        for (int i = 0; i < 4; ++i) { afr[i][0] = LDS_A(i, 0); afr[i][1] = LDS_A(i, 1); }
        #pragma unroll
        for (int j = 0; j < 2; ++j) { b0[j][0] = LDS_B(j, 0); b0[j][1] = LDS_B(j, 1); }
        b1[0] = LDS_B(2, 0); b1[1] = LDS_B(2, 1);
        if (tt + 1 < NT) { gl2lds16(aS[0] + 64 * (tt + 1), &S[ob][ldA[0]]);
                           gl2lds16(aS[1] + 64 * (tt + 1), &S[ob][ldA[1]]);
                           gl2lds16(aS[2] + 64 * (tt + 1), &S[ob][ldA[2]]);
                           gl2lds16(aS[3] + 64 * (tt + 1), &S[ob][ldA[3]]); }
        RAW_BARRIER();
        __builtin_amdgcn_s_setprio(1);
        #pragma unroll
        for (int i = 0; i < 4; ++i) {
            MM(i, 0, b0[0][0], b0[0][1]);
            MM(i, 1, b0[1][0], b0[1][1]);
            MM(i, 2, b1[0],    b1[1]);
        }
        __builtin_amdgcn_s_setprio(0);
        SCHED_FENCE(); RAW_BARRIER();
        #pragma unroll
        for (int i = 0; i < 4; ++i) { afr[i][0] = LDS_A(4 + i, 0); afr[i][1] = LDS_A(4 + i, 1); }
        if (tt + 2 < NT) { gl2lds16(bS[0] + 64 * (tt + 2), &S[bf][ldB[0]]);
                           gl2lds16(bS[1] + 64 * (tt + 2), &S[bf][ldB[1]]);
                           gl2lds16(bS[2] + 64 * (tt + 2), &S[bf][ldB[2]]); }
        RAW_BARRIER();
        __builtin_amdgcn_s_setprio(1);
        #pragma unroll
        for (int i = 0; i < 4; ++i) {
            MM(4 + i, 0, b0[0][0], b0[0][1]);
            MM(4 + i, 1, b0[1][0], b0[1][1]);
            MM(4 + i, 2, b1[0],    b1[1]);
        }
        __builtin_amdgcn_s_setprio(0);
        SCHED_FENCE();
        if (tt < NT - 2)       { WAIT_VM(3); }
        else if (tt == NT - 2) { WAIT_VM(0); }
        RAW_BARRIER();
        #undef LDS_A
        #undef LDS_B
        #undef MM
    }

    // ---- epilogue: LDS transpose (conflict-free COLP) + u16x8 stores ----
    u16* Ct = &S[0][0];                           // [256][COLP] u16 = 100.4 KB
    #pragma unroll
    for (int i = 0; i < 8; ++i) {
        int lrow = wm * 128 + 16 * i + 4 * g;
        #pragma unroll
        for (int j = 0; j < 3; ++j) {
            int lcol = wn * 48 + 16 * j + cid;
            #pragma unroll
            for (int r = 0; r < 4; ++r)
                Ct[(lrow + r) * COLP + lcol] = f2bf(acc[i][j][r]);
        }
    }
    RAW_BARRIER();
    #pragma unroll
    for (int it = 0; it < 12; ++it) {
        int f = t + 512 * it;                     // 6144 chunks = 256 rows x 24
        int row = f / 24, cch = f - row * 24;
        u16x8 v = *(const u16x8*)&Ct[row * COLP + cch * 8];
        *(u16x8*)&out[(size_t)(bm + row) * 768 + bn + cch * 8] = v;
    }
}

// ---------------- dq: flash pass over k, 128-q tile, computes L and Aq -------
__global__ __launch_bounds__(256) void dq_kernel(const u16* __restrict__ qk,
    const u16* __restrict__ qkT, float* __restrict__ L, u16* __restrict__ mid)
{
    const int flat = blockIdx.x;
    const int xcd = flat & 7, slot = flat >> 3;       // 96 slots per XCD
    const int bh = xcd * 12 + slot / 8;               // 12 bh per XCD
    const int q0 = (slot % 8) << 7;
    const int b = bh / H_, h = bh % H_;
    const u16* qbase = qk + (size_t)b * 1024 * 1536 + h * 64;
    const u16* kbase = qbase + 768;
    const u16* ktg = qkT + ((size_t)bh * 2 + 1) * 64 * 1024;   // K^T [y][1024]
    __shared__ __align__(16) u16 KB[2][8192];   // per buf: Kn [0,4096) | Kt [4096,8192)
    __shared__ __align__(16) u16 Ps[8192];
    const int t = threadIdx.x, w = t >> 6, l = t & 63, g = l >> 4, cid = l & 15;
    const int lr = l & 15, lc = l >> 4;

    #pragma unroll
    for (int h2 = 0; h2 < 2; ++h2)
        #pragma unroll
        for (int ch = 0; ch < 2; ++ch)
            gl2lds16(&qbase[(size_t)(q0 + 32 * w + 16 * h2 + lr) * 1536 + 32 * ch + 8 * lc],
                     &KB[0][(128 * (2 * w + h2) + 64 * ch + l) * 8]);
    __syncthreads();
    bf16x8 QF[2][2];
    #pragma unroll
    for (int jj = 0; jj < 2; ++jj)
        #pragma unroll
        for (int hh = 0; hh < 2; ++hh)
            QF[jj][hh] = *(const bf16x8*)&KB[0][(128 * (2 * w + jj) + 64 * hh + l) * 8];
    __syncthreads();   // all QF reads done before KB[0] is restaged

    auto stageK = [&](int buf, int kt) {   // 4 gl2lds per wave
        #pragma unroll
        for (int ch = 0; ch < 2; ++ch) {
            gl2lds16(&kbase[(size_t)(kt * 64 + 16 * w + lr) * 1536 + 32 * ch + 8 * lc],
                     &KB[buf][(128 * w + 64 * ch + l) * 8]);
            gl2lds16(&ktg[(size_t)(16 * w + lr) * 1024 + kt * 64 + 32 * ch + 8 * lc],
                     &KB[buf][4096 + (128 * w + 64 * ch + l) * 8]);
        }
    };

    f32x4 acc[2][4] = {};
    float lrun[2] = {0.0f, 0.0f};

    stageK(0, 0); stageK(1, 1);
    #pragma unroll 1
    for (int kt = 0; kt < 16; ++kt) {
        if (kt == 15) { WAIT_VM(0); } else { WAIT_VM(4); }
        RAW_BARRIER();
        const int buf = kt & 1;
        const u16* Kn = &KB[buf][0];
        const u16* Kt = &KB[buf][4096];
        f32x4 s[4][2];
        #pragma unroll
        for (int i = 0; i < 4; ++i) {
            bf16x8 a0 = *(const bf16x8*)&Kn[(128 * i + l) * 8];
            bf16x8 a1 = *(const bf16x8*)&Kn[(128 * i + 64 + l) * 8];
            #pragma unroll
            for (int jj = 0; jj < 2; ++jj) {
                f32x4 z = {0.f, 0.f, 0.f, 0.f};
                z = MFMA(a0, QF[jj][0], z, 0, 0, 0);
                z = MFMA(a1, QF[jj][1], z, 0, 0, 0);
                s[i][jj] = z;
            }
        }
        #pragma unroll
        for (int jj = 0; jj < 2; ++jj) {
            float psum = 0.0f;
            #pragma unroll
            for (int i = 0; i < 4; ++i) {
                u16x4 pv;
                #pragma unroll
                for (int r = 0; r < 4; ++r) {
                    float p = EXP2F(s[i][jj][r] * B2L_);
                    psum += p;
                    pv[r] = f2bf_rz(p);
                }
                *(u16x4*)&Ps[(128 * (2 * w + jj) + 32 * i + 16 * (g >> 1) + cid) * 8 + 4 * (g & 1)] = pv;
            }
            psum += __shfl_xor(psum, 16);
            psum += __shfl_xor(psum, 32);
            lrun[jj] += psum;
        }
        #pragma unroll
        for (int jj = 0; jj < 2; ++jj) {
            bf16x8 p0 = *(const bf16x8*)&Ps[(128 * (2 * w + jj) + l) * 8];
            bf16x8 p1 = *(const bf16x8*)&Ps[(128 * (2 * w + jj) + 64 + l) * 8];
            #pragma unroll
            for (int j = 0; j < 4; ++j) {
                acc[jj][j] = MFMA(p0, *(const bf16x8*)&Kt[(128 * j + l) * 8], acc[jj][j], 0, 0, 0);
                acc[jj][j] = MFMA(p1, *(const bf16x8*)&Kt[(128 * j + 64 + l) * 8], acc[jj][j], 0, 0, 0);
            }
        }
        RAW_BARRIER();
        if (kt + 2 < 16) stageK(buf, kt + 2);
    }
    #pragma unroll
    for (int jj = 0; jj < 2; ++jj) {
        if (g == 0)
            L[(size_t)bh * 1024 + q0 + 32 * w + 16 * jj + cid] = __logf(lrun[jj]);
        float linv = 1.0f / lrun[jj];
        #pragma unroll
        for (int r = 0; r < 4; ++r) {
            float fr = __shfl(linv, 4 * g + r);
            int row = q0 + 32 * w + 16 * jj + 4 * g + r;
            #pragma unroll
            for (int j = 0; j < 4; ++j)
                mid[(size_t)(b * 1024 + row) * 4608 + h * 64 + 16 * j + cid] = f2bf(acc[jj][j][r] * fr);
        }
    }
}

// ---------------- dk: Ak[k] = sum_q exp(beta*S - L[q]) q, 128-k tile --------
__global__ __launch_bounds__(256) void dk_kernel(const u16* __restrict__ qk,
    const u16* __restrict__ qkT, const float* __restrict__ L, u16* __restrict__ mid)
{
    const int flat = blockIdx.x;
    const int xcd = flat & 7, slot = flat >> 3;
    const int bh = xcd * 12 + slot / 8;
    const int k0 = (slot % 8) << 7;
    const int b = bh / H_, h = bh % H_;
    const u16* qbase = qk + (size_t)b * 1024 * 1536 + h * 64;
    const u16* kbase = qbase + 768;
    const u16* qtg = qkT + ((size_t)bh * 2 + 0) * 64 * 1024;   // Q^T [y][1024]
    __shared__ __align__(16) u16 KB[2][8192];   // per buf: Qn [0,4096) | Qt [4096,8192)
    __shared__ __align__(16) u16 Ps[8192];
    const int t = threadIdx.x, w = t >> 6, l = t & 63, g = l >> 4, cid = l & 15;
    const int lr = l & 15, lc = l >> 4;

    #pragma unroll
    for (int h2 = 0; h2 < 2; ++h2)
        #pragma unroll
        for (int ch = 0; ch < 2; ++ch)
            gl2lds16(&kbase[(size_t)(k0 + 32 * w + 16 * h2 + lr) * 1536 + 32 * ch + 8 * lc],
                     &KB[0][(128 * (2 * w + h2) + 64 * ch + l) * 8]);
    __syncthreads();
    bf16x8 KF[2][2];
    #pragma unroll
    for (int jj = 0; jj < 2; ++jj)
        #pragma unroll
        for (int hh = 0; hh < 2; ++hh)
            KF[jj][hh] = *(const bf16x8*)&KB[0][(128 * (2 * w + jj) + 64 * hh + l) * 8];
    __syncthreads();

    auto stageQ = [&](int buf, int qt) {   // 4 gl2lds per wave
        #pragma unroll
        for (int ch = 0; ch < 2; ++ch) {
            gl2lds16(&qbase[(size_t)(qt * 64 + 16 * w + lr) * 1536 + 32 * ch + 8 * lc],
                     &KB[buf][(128 * w + 64 * ch + l) * 8]);
            gl2lds16(&qtg[(size_t)(16 * w + lr) * 1024 + qt * 64 + 32 * ch + 8 * lc],
                     &KB[buf][4096 + (128 * w + 64 * ch + l) * 8]);
        }
    };

    f32x4 acc[2][4] = {};
    stageQ(0, 0); stageQ(1, 1);
    #pragma unroll 1
    for (int qt = 0; qt < 16; ++qt) {
        if (qt == 15) { WAIT_VM(0); } else { WAIT_VM(4); }
        RAW_BARRIER();
        const int buf = qt & 1;
        const u16* Qn = &KB[buf][0];
        const u16* Qt = &KB[buf][4096];
        #pragma unroll
        for (int i = 0; i < 4; ++i) {
            bf16x8 a0 = *(const bf16x8*)&Qn[(128 * i + l) * 8];
            bf16x8 a1 = *(const bf16x8*)&Qn[(128 * i + 64 + l) * 8];
            f32x4 lv = *(const f32x4*)&L[(size_t)bh * 1024 + qt * 64 + 16 * i + 4 * g];
            f32x4 lv2;
            #pragma unroll
            for (int r = 0; r < 4; ++r) lv2[r] = lv[r] * L2E_;
            #pragma unroll
            for (int jj = 0; jj < 2; ++jj) {
                f32x4 z = {0.f, 0.f, 0.f, 0.f};
                z = MFMA(a0, KF[jj][0], z, 0, 0, 0);
                z = MFMA(a1, KF[jj][1], z, 0, 0, 0);
                u16x4 pv;
                #pragma unroll
                for (int r = 0; r < 4; ++r)
                    pv[r] = f2bf_rz(EXP2F(fmaf(z[r], B2L_, -lv2[r])));
                *(u16x4*)&Ps[(128 * (2 * w + jj) + 32 * i + 16 * (g >> 1) + cid) * 8 + 4 * (g & 1)] = pv;
            }
        }
        #pragma unroll
        for (int jj = 0; jj < 2; ++jj) {
            bf16x8 p0 = *(const bf16x8*)&Ps[(128 * (2 * w + jj) + l) * 8];
            bf16x8 p1 = *(const bf16x8*)&Ps[(128 * (2 * w + jj) + 64 + l) * 8];
            #pragma unroll
            for (int j = 0; j < 4; ++j) {
                acc[jj][j] = MFMA(p0, *(const bf16x8*)&Qt[(128 * j + l) * 8], acc[jj][j], 0, 0, 0);
                acc[jj][j] = MFMA(p1, *(const bf16x8*)&Qt[(128 * j + 64 + l) * 8], acc[jj][j], 0, 0, 0);
            }
        }
        RAW_BARRIER();
        if (qt + 2 < 16) stageQ(buf, qt + 2);
    }
    #pragma unroll
    for (int jj = 0; jj < 2; ++jj)
        #pragma unroll
        for (int r = 0; r < 4; ++r) {
            int row = k0 + 32 * w + 16 * jj + 4 * g + r;
            #pragma unroll
            for (int j = 0; j < 4; ++j)
                mid[(size_t)(b * 1024 + row) * 4608 + 768 + h * 64 + 16 * j + cid] = f2bf(acc[jj][j][r]);
        }
}

// ---------------------------------------------------------------------------
extern "C" void kernel_launch(void* const* d_in, const int* in_sizes, int n_in,
                              void* d_out, int out_size, void* d_ws, size_t ws_size,
                              hipStream_t stream)
{
    const float* x     = (const float*)d_in[0];
    const float* gamma = (const float*)d_in[1];
    const float* betap = (const float*)d_in[2];
    const float* Wq    = (const float*)d_in[3];
    const float* Wk    = (const float*)d_in[4];
    const float* xi    = (const float*)d_in[5];
    float* xc = (float*)d_out;

    char* p = (char*)d_ws;
    u16* wcat_bf  = (u16*)p; p += (size_t)4608 * 768 * 2;   // [Wq;Wk;xi] rows
    u16* wcatT_bf = (u16*)p; p += (size_t)768 * 4608 * 2;
    u16* g_bf     = (u16*)p; p += (size_t)NTOK * 768 * 2;
    u16* qk_bf    = (u16*)p; p += (size_t)NTOK * 1536 * 2;
    u16* qkT_bf   = (u16*)p; p += (size_t)96 * 2 * 64 * 1024 * 2;
    u16* mid_bf   = (u16*)p; p += (size_t)NTOK * 4608 * 2;
    float* L      = (float*)p; p += (size_t)96 * 1024 * 4;
    // part[2][8192][768] bf16 = 25.17 MB ALIASES qk_bf (25.17 MB exactly):
    // qk is dead once dq/dk complete; part is consumed by reduce_ln before
    // the next step's gemm_fwd rewrites qk.
    u16* part = qk_bf;
    (void)ws_size; (void)in_sizes; (void)n_in; (void)out_size;

    hipMemcpyAsync(xc, x, (size_t)NTOK * 768 * 4, hipMemcpyDeviceToDevice, stream);

    convert_bf<<<576, 256, 0, stream>>>(Wq, wcat_bf, 147456);
    convert_bf<<<576, 256, 0, stream>>>(Wk, wcat_bf + 768 * 768, 147456);
    convert_bf<<<2304, 256, 0, stream>>>(xi, wcat_bf + 2 * 768 * 768, 589824);
    transpose_bf<<<dim3(72, 12), 256, 0, stream>>>(Wq, Wk, xi, wcatT_bf);

    // g_0 = LN(x)
    ln_kernel<<<NTOK, 256, 0, stream>>>(x, gamma, betap, g_bf);

    for (int step = 0; step < STEPS_; ++step) {
        // fused: qk (+qkT) and relu-mid in one N=4608 GEMM (256x192, 2-phase)
        gemm_fwd<<<768, 512, 0, stream>>>(
            g_bf, wcat_bf, qk_bf, qkT_bf, mid_bf);
        // Aq (+L), Ak  (XCD-swizzled, ping-pong staged)
        dq_kernel<<<768, 256, 0, stream>>>(qk_bf, qkT_bf, L, mid_bf);
        dk_kernel<<<768, 256, 0, stream>>>(qk_bf, qkT_bf, L, mid_bf);
        // part[z] = mid . Wcat (2 K-halves, 256x192, transposed epilogue)
        gemm_upd<<<256, 512, 0, stream>>>(mid_bf, wcatT_bf, part);
        // xc += alpha*(P0+P1); g = LN(xc)   (fused)
        reduce_ln<<<NTOK, 192, 0, stream>>>(part, xc, gamma, betap, g_bf);
    }
}